// Round 1
// baseline (5549.112 us; speedup 1.0000x reference)
//
#include <hip/hip_runtime.h>
#include <cstdint>
#include <cfloat>
#include <cmath>

// ---------------------------------------------------------------------------
// 3x3 conv, pad 1, optional input-relu, optional skip-add (elementwise).
// Spatial tile 16x16 per block, 256 threads.
// Thread layout: tid&63 -> pixel group (row = pg>>2, 4 consecutive x),
//                tid>>6 -> co-quad (Q = COUT/16 quads per thread).
// Weights staged in LDS transposed [ci][k][co] for float4 reads over co.
// Cin chunked at 16 to bound LDS (<= 40.3 KB for 32x32).
// ---------------------------------------------------------------------------
template<int CIN, int COUT>
__global__ __launch_bounds__(256) void conv3x3_k(
    const float* __restrict__ in, const float* __restrict__ w,
    const float* __restrict__ bias, const float* __restrict__ skip,
    float* __restrict__ out, int H, int tx, int relu_in)
{
    constexpr int CC = (CIN < 16) ? CIN : 16;   // ci chunk
    constexpr int Q  = COUT / 16;               // co-quads per thread
    __shared__ float in_t[CC][18][19];          // stride 19: <=2-way conflicts
    __shared__ __align__(16) float wt[CC * 9 * COUT];

    const int n    = blockIdx.y;
    const int tile = blockIdx.x;
    const int ty0  = (tile / tx) * 16, tx0 = (tile % tx) * 16;
    const int tid  = threadIdx.x;
    const int pg   = tid & 63, cq = tid >> 6;
    const int row  = pg >> 2, x0 = (pg & 3) << 2;

    float acc[Q][4][4];
    #pragma unroll
    for (int q = 0; q < Q; ++q)
        #pragma unroll
        for (int a = 0; a < 4; ++a)
            #pragma unroll
            for (int b = 0; b < 4; ++b) acc[q][a][b] = 0.f;

    const size_t HH = (size_t)H * H;
    const float* inN = in + (size_t)n * CIN * HH;

    for (int cb = 0; cb < CIN; cb += CC) {
        if (cb) __syncthreads();
        // stage weights transposed: wt[(ci*9+k)*COUT+co] = w[((co*CIN+cb+ci)*9)+k]
        for (int i = tid; i < CC * 9 * COUT; i += 256) {
            int co = i % COUT; int rest = i / COUT; int k = rest % 9; int ci = rest / 9;
            wt[i] = w[((size_t)co * CIN + cb + ci) * 9 + k];
        }
        // stage input tile (with halo, zero-padded, optional relu)
        for (int i = tid; i < CC * 18 * 18; i += 256) {
            int ci = i / 324; int r = (i / 18) % 18; int c = i % 18;
            int gy = ty0 - 1 + r, gx = tx0 - 1 + c;
            float v = 0.f;
            if (gy >= 0 && gy < H && gx >= 0 && gx < H)
                v = inN[(size_t)(cb + ci) * HH + (size_t)gy * H + gx];
            if (relu_in) v = fmaxf(v, 0.f);
            in_t[ci][r][c] = v;
        }
        __syncthreads();

        for (int ci = 0; ci < CC; ++ci) {
            #pragma unroll
            for (int ky = 0; ky < 3; ++ky) {
                float v[6];
                #pragma unroll
                for (int j = 0; j < 6; ++j) v[j] = in_t[ci][row + ky][x0 + j];
                #pragma unroll
                for (int kx = 0; kx < 3; ++kx) {
                    #pragma unroll
                    for (int q = 0; q < Q; ++q) {
                        const float4 wv = *(const float4*)&wt[(ci * 9 + ky * 3 + kx) * COUT + (cq + q * 4) * 4];
                        #pragma unroll
                        for (int px = 0; px < 4; ++px) {
                            acc[q][0][px] = fmaf(v[kx + px], wv.x, acc[q][0][px]);
                            acc[q][1][px] = fmaf(v[kx + px], wv.y, acc[q][1][px]);
                            acc[q][2][px] = fmaf(v[kx + px], wv.z, acc[q][2][px]);
                            acc[q][3][px] = fmaf(v[kx + px], wv.w, acc[q][3][px]);
                        }
                    }
                }
            }
        }
    }

    // epilogue: +bias, optional skip add, float4 stores
    const int gy = ty0 + row, gx0 = tx0 + x0;
    #pragma unroll
    for (int q = 0; q < Q; ++q) {
        const int cob = (cq + q * 4) * 4;
        #pragma unroll
        for (int cs = 0; cs < 4; ++cs) {
            const int co = cob + cs;
            const size_t off = ((size_t)n * COUT + co) * HH + (size_t)gy * H + gx0;
            const float bv = bias[co];
            float4 o;
            o.x = acc[q][cs][0] + bv;
            o.y = acc[q][cs][1] + bv;
            o.z = acc[q][cs][2] + bv;
            o.w = acc[q][cs][3] + bv;
            if (skip) {
                const float4 s = *(const float4*)(skip + off);
                o.x += s.x; o.y += s.y; o.z += s.z; o.w += s.w;
            }
            *(float4*)(out + off) = o;
        }
    }
}

// ---------------------------------------------------------------------------
// maxpool 3x3 stride 2 pad 1 (-inf identity), NCHW
// ---------------------------------------------------------------------------
__global__ __launch_bounds__(256) void maxpool_k(
    const float* __restrict__ in, float* __restrict__ out, int NC, int H)
{
    const int HP = H >> 1;
    const size_t total = (size_t)NC * HP * HP;
    size_t idx = (size_t)blockIdx.x * 256 + threadIdx.x;
    if (idx >= total) return;
    const int px = (int)(idx % HP);
    size_t r = idx / HP;
    const int py = (int)(r % HP);
    const size_t nc = r / HP;
    const float* p = in + nc * (size_t)H * H;
    float m = -FLT_MAX;
    #pragma unroll
    for (int dy = 0; dy < 3; ++dy) {
        const int y = 2 * py - 1 + dy;
        if (y < 0 || y >= H) continue;
        #pragma unroll
        for (int dx = 0; dx < 3; ++dx) {
            const int x = 2 * px - 1 + dx;
            if (x < 0 || x >= H) continue;
            m = fmaxf(m, p[(size_t)y * H + x]);
        }
    }
    out[idx] = m;
}

// ---------------------------------------------------------------------------
// C[M,N] = act(A[M,K] @ B[N,K]^T + bias[N]); 64x32 tile, KT=32
// ---------------------------------------------------------------------------
__global__ __launch_bounds__(256) void gemm_k(
    const float* __restrict__ A, const float* __restrict__ B,
    const float* __restrict__ bias, float* __restrict__ C,
    int M, int N, int K, int relu)
{
    __shared__ float As[64][33];
    __shared__ float Bs[32][33];
    const int m0 = blockIdx.x * 64, n0 = blockIdx.y * 32;
    const int tid = threadIdx.x;
    const int col = tid & 31, rowg = tid >> 5;
    float acc[8] = {0, 0, 0, 0, 0, 0, 0, 0};
    for (int k0 = 0; k0 < K; k0 += 32) {
        for (int i = tid; i < 64 * 32; i += 256) {
            int r = i >> 5, c = i & 31;
            As[r][c] = A[(size_t)(m0 + r) * K + k0 + c];
        }
        for (int i = tid; i < 32 * 32; i += 256) {
            int r = i >> 5, c = i & 31;
            Bs[r][c] = B[(size_t)(n0 + r) * K + k0 + c];
        }
        __syncthreads();
        #pragma unroll
        for (int k = 0; k < 32; ++k) {
            const float b = Bs[col][k];
            #pragma unroll
            for (int j = 0; j < 8; ++j)
                acc[j] = fmaf(As[rowg * 8 + j][k], b, acc[j]);
        }
        __syncthreads();
    }
    const int n = n0 + col;
    const float bv = bias[n];
    #pragma unroll
    for (int j = 0; j < 8; ++j) {
        float v = acc[j] + bv;
        if (relu) v = fmaxf(v, 0.f);
        C[(size_t)(m0 + rowg * 8 + j) * N + n] = v;
    }
}

// ---------------------------------------------------------------------------
// CBAM (with leading relu): one block per image, x is (32,16,16)
// ---------------------------------------------------------------------------
__global__ __launch_bounds__(256) void cbam_k(
    const float* __restrict__ in, const float* __restrict__ fc1,
    const float* __restrict__ fc2, const float* __restrict__ spw,
    float* __restrict__ out)
{
    __shared__ float xl[32][257];
    __shared__ float cmean[32], cmax[32], hidm[8], hidx[8], ca[32];
    __shared__ float spm[256], spx[256], sa[256];
    const int n = blockIdx.x, tid = threadIdx.x;
    const float* inN = in + (size_t)n * 8192;
    for (int c = 0; c < 32; ++c) xl[c][tid] = fmaxf(inN[c * 256 + tid], 0.f);
    __syncthreads();
    if (tid < 32) {
        float s = 0.f, m = -FLT_MAX;
        for (int p = 0; p < 256; ++p) { float v = xl[tid][p]; s += v; m = fmaxf(m, v); }
        cmean[tid] = s * (1.f / 256.f); cmax[tid] = m;
    }
    __syncthreads();
    if (tid < 8) {
        float sm = 0.f, sx = 0.f;
        for (int c = 0; c < 32; ++c) {
            float f = fc1[tid * 32 + c];
            sm += f * cmean[c]; sx += f * cmax[c];
        }
        hidm[tid] = fmaxf(sm, 0.f); hidx[tid] = fmaxf(sx, 0.f);
    }
    __syncthreads();
    if (tid < 32) {
        float s = 0.f;
        for (int h = 0; h < 8; ++h) s += fc2[tid * 8 + h] * (hidm[h] + hidx[h]);
        ca[tid] = 1.f / (1.f + expf(-s));
    }
    __syncthreads();
    {
        float s = 0.f, m = -FLT_MAX;
        for (int c = 0; c < 32; ++c) {
            float v = xl[c][tid] * ca[c];
            xl[c][tid] = v;
            s += v; m = fmaxf(m, v);
        }
        spm[tid] = s * (1.f / 32.f); spx[tid] = m;
    }
    __syncthreads();
    {
        const int y = tid >> 4, x = tid & 15;
        float s = 0.f;
        for (int ky = 0; ky < 7; ++ky) {
            const int yy = y + ky - 3;
            if (yy < 0 || yy >= 16) continue;
            for (int kx = 0; kx < 7; ++kx) {
                const int xx = x + kx - 3;
                if (xx < 0 || xx >= 16) continue;
                const int p = yy * 16 + xx;
                s += spm[p] * spw[ky * 7 + kx] + spx[p] * spw[49 + ky * 7 + kx];
            }
        }
        sa[tid] = 1.f / (1.f + expf(-s));
    }
    __syncthreads();
    float* outN = out + (size_t)n * 8192;
    const float sav = sa[tid];
    for (int c = 0; c < 32; ++c) outN[c * 256 + tid] = xl[c][tid] * sav;
}

// ---------------------------------------------------------------------------
// GRU scan: 8 blocks (one per batch column), 384 threads (one Whh row each,
// register-cached). Sequential over T=64 inside the kernel.
// ---------------------------------------------------------------------------
__global__ __launch_bounds__(384) void gru_k(
    const float* __restrict__ gi, const float* __restrict__ done,
    const float* __restrict__ h0, const float* __restrict__ whh,
    const float* __restrict__ bhh, float* __restrict__ hidden)
{
    const int b = blockIdx.x, j = threadIdx.x;
    __shared__ __align__(16) float hl[128];
    __shared__ float gh[384];
    float4 wr[32];
    const float4* wrow = (const float4*)(whh + (size_t)j * 128);
    #pragma unroll
    for (int i = 0; i < 32; ++i) wr[i] = wrow[i];
    const float bj = bhh[j];
    if (j < 128) hl[j] = h0[b * 128 + j];
    __syncthreads();
    for (int t = 0; t < 64; ++t) {
        const int rowi = t * 8 + b;
        const float dmask = 1.f - done[rowi];
        if (j < 128) hl[j] *= dmask;
        __syncthreads();
        float s = bj;
        const float4* h4 = (const float4*)hl;
        #pragma unroll
        for (int i = 0; i < 32; ++i) {
            const float4 h = h4[i];
            s = fmaf(wr[i].x, h.x, s);
            s = fmaf(wr[i].y, h.y, s);
            s = fmaf(wr[i].z, h.z, s);
            s = fmaf(wr[i].w, h.w, s);
        }
        gh[j] = s;
        __syncthreads();
        if (j < 128) {
            const float* gir = gi + (size_t)rowi * 384;
            const float r = 1.f / (1.f + expf(-(gir[j] + gh[j])));
            const float z = 1.f / (1.f + expf(-(gir[128 + j] + gh[128 + j])));
            const float nn = tanhf(gir[256 + j] + r * gh[256 + j]);
            const float hm = hl[j];
            const float hn = (1.f - z) * nn + z * hm;
            hl[j] = hn;
            hidden[(size_t)rowi * 128 + j] = hn;
        }
        __syncthreads();
    }
}

// ---------------------------------------------------------------------------
// actor/critic heads -> out (512, 4) = [logit0, logit1, logit2, value]
// ---------------------------------------------------------------------------
__global__ __launch_bounds__(256) void heads_k(
    const float* __restrict__ hidden, const float* __restrict__ aw,
    const float* __restrict__ ab, const float* __restrict__ cw,
    const float* __restrict__ cb, float* __restrict__ out)
{
    const int idx = blockIdx.x * 256 + threadIdx.x;  // 2048
    const int m = idx >> 2, c = idx & 3;
    const float* h = hidden + (size_t)m * 128;
    const float* w = (c < 3) ? (aw + (size_t)c * 128) : cw;
    float s = (c < 3) ? ab[c] : cb[0];
    for (int k = 0; k < 128; ++k) s = fmaf(h[k], w[k], s);
    out[idx] = s;
}

// ---------------------------------------------------------------------------
extern "C" void kernel_launch(void* const* d_in, const int* in_sizes, int n_in,
                              void* d_out, int out_size, void* d_ws, size_t ws_size,
                              hipStream_t stream)
{
    const float* x      = (const float*)d_in[0];
    const float* done   = (const float*)d_in[1];
    const float* gstate = (const float*)d_in[2];
    const float* s0_cw  = (const float*)d_in[3];
    const float* s0_cb  = (const float*)d_in[4];
    const float* s0_rw  = (const float*)d_in[5];
    const float* s0_rb  = (const float*)d_in[6];
    const float* s1_cw  = (const float*)d_in[7];
    const float* s1_cb  = (const float*)d_in[8];
    const float* s1_rw  = (const float*)d_in[9];
    const float* s1_rb  = (const float*)d_in[10];
    const float* s2_cw  = (const float*)d_in[11];
    const float* s2_cb  = (const float*)d_in[12];
    const float* s2_rw  = (const float*)d_in[13];
    const float* s2_rb  = (const float*)d_in[14];
    const float* cfc1   = (const float*)d_in[15];
    const float* cfc2   = (const float*)d_in[16];
    const float* cspw   = (const float*)d_in[17];
    const float* fc_w   = (const float*)d_in[18];
    const float* fc_b   = (const float*)d_in[19];
    const float* gwih   = (const float*)d_in[20];
    const float* gbih   = (const float*)d_in[22];
    const float* gwhh   = (const float*)d_in[21];
    const float* gbhh   = (const float*)d_in[23];
    const float* aw     = (const float*)d_in[24];
    const float* ab     = (const float*)d_in[25];
    const float* cwt    = (const float*)d_in[26];
    const float* cbs    = (const float*)d_in[27];
    float* out = (float*)d_out;
    float* ws  = (float*)d_ws;

    // ws layout (floats); peak ~268 MB
    float* P0 = ws;                 // 33,554,432 floats
    float* T  = ws + 33554432;      // 33,554,432 floats
    float* S1P = T + 16777216;      // s1 pool out (16,777,216)
    float* X0  = P0 + 16777216;     // s2 pool out (4,194,304)
    float* TM  = P0 + 20971520;     // s2 res tmp  (4,194,304)
    float* CBO = P0 + 25165824;     // cbam out    (4,194,304)

    // ---- stage 0: entry conv (6->16, 128x128) + pool, chunks of 64 images ----
    for (int c = 0; c < 8; ++c) {
        const float* xin = x + (size_t)c * 64 * 6 * 128 * 128;
        conv3x3_k<6, 16><<<dim3(64, 64), 256, 0, stream>>>(xin, s0_cw, s0_cb, nullptr, T, 128, 8, 0);
        maxpool_k<<<(64 * 16 * 64 * 64) / 256, 256, 0, stream>>>(T, P0 + (size_t)c * 4194304, 64 * 16, 128);
    }
    // ---- stage 0 resblocks (16ch, 64x64) ----
    {
        const int RW = 16 * 16 * 9;
        conv3x3_k<16, 16><<<dim3(16, 512), 256, 0, stream>>>(P0, s0_rw + 0 * RW, s0_rb + 0,  nullptr, T,  64, 4, 1);
        conv3x3_k<16, 16><<<dim3(16, 512), 256, 0, stream>>>(T,  s0_rw + 1 * RW, s0_rb + 16, P0,      P0, 64, 4, 1);
        conv3x3_k<16, 16><<<dim3(16, 512), 256, 0, stream>>>(P0, s0_rw + 2 * RW, s0_rb + 32, nullptr, T,  64, 4, 1);
        conv3x3_k<16, 16><<<dim3(16, 512), 256, 0, stream>>>(T,  s0_rw + 3 * RW, s0_rb + 48, P0,      P0, 64, 4, 1);
    }
    // ---- stage 1: entry conv (16->32, 64x64) + pool, chunks of 128 images ----
    for (int c = 0; c < 4; ++c) {
        conv3x3_k<16, 32><<<dim3(16, 128), 256, 0, stream>>>(P0 + (size_t)c * 8388608, s1_cw, s1_cb, nullptr, T, 64, 4, 0);
        maxpool_k<<<16384, 256, 0, stream>>>(T, S1P + (size_t)c * 4194304, 128 * 32, 64);
    }
    // ---- stage 1 resblocks (32ch, 32x32) ----
    {
        const int RW = 32 * 32 * 9;
        conv3x3_k<32, 32><<<dim3(4, 512), 256, 0, stream>>>(S1P, s1_rw + 0 * RW, s1_rb + 0,  nullptr, P0,  32, 2, 1);
        conv3x3_k<32, 32><<<dim3(4, 512), 256, 0, stream>>>(P0,  s1_rw + 1 * RW, s1_rb + 32, S1P,     S1P, 32, 2, 1);
        conv3x3_k<32, 32><<<dim3(4, 512), 256, 0, stream>>>(S1P, s1_rw + 2 * RW, s1_rb + 64, nullptr, P0,  32, 2, 1);
        conv3x3_k<32, 32><<<dim3(4, 512), 256, 0, stream>>>(P0,  s1_rw + 3 * RW, s1_rb + 96, S1P,     S1P, 32, 2, 1);
    }
    // ---- stage 2: entry conv (32->32, 32x32) + pool ----
    conv3x3_k<32, 32><<<dim3(4, 512), 256, 0, stream>>>(S1P, s2_cw, s2_cb, nullptr, P0, 32, 2, 0);
    maxpool_k<<<16384, 256, 0, stream>>>(P0, X0, 512 * 32, 32);
    // ---- stage 2 resblocks (32ch, 16x16) ----
    {
        const int RW = 32 * 32 * 9;
        conv3x3_k<32, 32><<<dim3(1, 512), 256, 0, stream>>>(X0, s2_rw + 0 * RW, s2_rb + 0,  nullptr, TM, 16, 1, 1);
        conv3x3_k<32, 32><<<dim3(1, 512), 256, 0, stream>>>(TM, s2_rw + 1 * RW, s2_rb + 32, X0,      X0, 16, 1, 1);
        conv3x3_k<32, 32><<<dim3(1, 512), 256, 0, stream>>>(X0, s2_rw + 2 * RW, s2_rb + 64, nullptr, TM, 16, 1, 1);
        conv3x3_k<32, 32><<<dim3(1, 512), 256, 0, stream>>>(TM, s2_rw + 3 * RW, s2_rb + 96, X0,      X0, 16, 1, 1);
    }
    // ---- relu + CBAM ----
    cbam_k<<<512, 256, 0, stream>>>(X0, cfc1, cfc2, cspw, CBO);
    // ---- FC 8192->256 (+relu) ----
    float* FEAT = T;
    gemm_k<<<dim3(8, 8), 256, 0, stream>>>(CBO, fc_w, fc_b, FEAT, 512, 256, 8192, 1);
    // ---- gi = feat @ Wih^T + bih ----
    float* GI = T + 131072;
    gemm_k<<<dim3(8, 12), 256, 0, stream>>>(FEAT, gwih, gbih, GI, 512, 384, 256, 0);
    // ---- GRU scan ----
    float* HID = T + 131072 + 196608;
    gru_k<<<8, 384, 0, stream>>>(GI, done, gstate, gwhh, gbhh, HID);
    // ---- heads ----
    heads_k<<<8, 256, 0, stream>>>(HID, aw, ab, cwt, cbs, out);
}

// Round 2
// 4213.310 us; speedup vs baseline: 1.3170x; 1.3170x over previous
//
#include <hip/hip_runtime.h>
#include <cstdint>
#include <cfloat>
#include <cmath>

// ---------------------------------------------------------------------------
// 3x3 conv, pad 1, optional input-relu, optional skip-add (elementwise).
// Spatial tile 16x16 per block, 256 threads.  (UNCHANGED this round.)
// ---------------------------------------------------------------------------
template<int CIN, int COUT>
__global__ __launch_bounds__(256) void conv3x3_k(
    const float* __restrict__ in, const float* __restrict__ w,
    const float* __restrict__ bias, const float* __restrict__ skip,
    float* __restrict__ out, int H, int tx, int relu_in)
{
    constexpr int CC = (CIN < 16) ? CIN : 16;   // ci chunk
    constexpr int Q  = COUT / 16;               // co-quads per thread
    __shared__ float in_t[CC][18][19];          // stride 19: <=2-way conflicts
    __shared__ __align__(16) float wt[CC * 9 * COUT];

    const int n    = blockIdx.y;
    const int tile = blockIdx.x;
    const int ty0  = (tile / tx) * 16, tx0 = (tile % tx) * 16;
    const int tid  = threadIdx.x;
    const int pg   = tid & 63, cq = tid >> 6;
    const int row  = pg >> 2, x0 = (pg & 3) << 2;

    float acc[Q][4][4];
    #pragma unroll
    for (int q = 0; q < Q; ++q)
        #pragma unroll
        for (int a = 0; a < 4; ++a)
            #pragma unroll
            for (int b = 0; b < 4; ++b) acc[q][a][b] = 0.f;

    const size_t HH = (size_t)H * H;
    const float* inN = in + (size_t)n * CIN * HH;

    for (int cb = 0; cb < CIN; cb += CC) {
        if (cb) __syncthreads();
        for (int i = tid; i < CC * 9 * COUT; i += 256) {
            int co = i % COUT; int rest = i / COUT; int k = rest % 9; int ci = rest / 9;
            wt[i] = w[((size_t)co * CIN + cb + ci) * 9 + k];
        }
        for (int i = tid; i < CC * 18 * 18; i += 256) {
            int ci = i / 324; int r = (i / 18) % 18; int c = i % 18;
            int gy = ty0 - 1 + r, gx = tx0 - 1 + c;
            float v = 0.f;
            if (gy >= 0 && gy < H && gx >= 0 && gx < H)
                v = inN[(size_t)(cb + ci) * HH + (size_t)gy * H + gx];
            if (relu_in) v = fmaxf(v, 0.f);
            in_t[ci][r][c] = v;
        }
        __syncthreads();

        for (int ci = 0; ci < CC; ++ci) {
            #pragma unroll
            for (int ky = 0; ky < 3; ++ky) {
                float v[6];
                #pragma unroll
                for (int j = 0; j < 6; ++j) v[j] = in_t[ci][row + ky][x0 + j];
                #pragma unroll
                for (int kx = 0; kx < 3; ++kx) {
                    #pragma unroll
                    for (int q = 0; q < Q; ++q) {
                        const float4 wv = *(const float4*)&wt[(ci * 9 + ky * 3 + kx) * COUT + (cq + q * 4) * 4];
                        #pragma unroll
                        for (int px = 0; px < 4; ++px) {
                            acc[q][0][px] = fmaf(v[kx + px], wv.x, acc[q][0][px]);
                            acc[q][1][px] = fmaf(v[kx + px], wv.y, acc[q][1][px]);
                            acc[q][2][px] = fmaf(v[kx + px], wv.z, acc[q][2][px]);
                            acc[q][3][px] = fmaf(v[kx + px], wv.w, acc[q][3][px]);
                        }
                    }
                }
            }
        }
    }

    const int gy = ty0 + row, gx0 = tx0 + x0;
    #pragma unroll
    for (int q = 0; q < Q; ++q) {
        const int cob = (cq + q * 4) * 4;
        #pragma unroll
        for (int cs = 0; cs < 4; ++cs) {
            const int co = cob + cs;
            const size_t off = ((size_t)n * COUT + co) * HH + (size_t)gy * H + gx0;
            const float bv = bias[co];
            float4 o;
            o.x = acc[q][cs][0] + bv;
            o.y = acc[q][cs][1] + bv;
            o.z = acc[q][cs][2] + bv;
            o.w = acc[q][cs][3] + bv;
            if (skip) {
                const float4 s = *(const float4*)(skip + off);
                o.x += s.x; o.y += s.y; o.z += s.z; o.w += s.w;
            }
            *(float4*)(out + off) = o;
        }
    }
}

// ---------------------------------------------------------------------------
// maxpool 3x3 stride 2 pad 1, NCHW  (UNCHANGED)
// ---------------------------------------------------------------------------
__global__ __launch_bounds__(256) void maxpool_k(
    const float* __restrict__ in, float* __restrict__ out, int NC, int H)
{
    const int HP = H >> 1;
    const size_t total = (size_t)NC * HP * HP;
    size_t idx = (size_t)blockIdx.x * 256 + threadIdx.x;
    if (idx >= total) return;
    const int px = (int)(idx % HP);
    size_t r = idx / HP;
    const int py = (int)(r % HP);
    const size_t nc = r / HP;
    const float* p = in + nc * (size_t)H * H;
    float m = -FLT_MAX;
    #pragma unroll
    for (int dy = 0; dy < 3; ++dy) {
        const int y = 2 * py - 1 + dy;
        if (y < 0 || y >= H) continue;
        #pragma unroll
        for (int dx = 0; dx < 3; ++dx) {
            const int x = 2 * px - 1 + dx;
            if (x < 0 || x >= H) continue;
            m = fmaxf(m, p[(size_t)y * H + x]);
        }
    }
    out[idx] = m;
}

// ---------------------------------------------------------------------------
// Split-K GEMM: partial[s][M][N] += A[M,K-chunk] @ B[N,K-chunk]^T
// 64x64 tile, 256 threads (thread = 4x4 micro-tile), k-major LDS (b128 reads).
// Grid: (M/64, N/64, K/KC). Deterministic (no atomics).
// ---------------------------------------------------------------------------
__global__ __launch_bounds__(256) void gemm_splitk_k(
    const float* __restrict__ A, const float* __restrict__ B,
    float* __restrict__ partial, int M, int N, int K, int KC)
{
    __shared__ __align__(16) float As[32][65];   // [k][m]
    __shared__ __align__(16) float Bs[32][65];   // [k][n]
    const int m0 = blockIdx.x * 64, n0 = blockIdx.y * 64;
    const int kbase = blockIdx.z * KC;
    const int tid = threadIdx.x;
    const int tx = tid & 15, ty = tid >> 4;      // n-quad, m-quad

    float acc[4][4];
    #pragma unroll
    for (int i = 0; i < 4; ++i)
        #pragma unroll
        for (int j = 0; j < 4; ++j) acc[i][j] = 0.f;

    for (int k0 = kbase; k0 < kbase + KC; k0 += 32) {
        // stage: A[m0+m][k0+k] -> As[k][m]; bank=(k+m)%32 conflict-free
        for (int i = tid; i < 64 * 32; i += 256) {
            const int m = i >> 5, k = i & 31;
            As[k][m] = A[(size_t)(m0 + m) * K + k0 + k];
        }
        for (int i = tid; i < 64 * 32; i += 256) {
            const int n = i >> 5, k = i & 31;
            Bs[k][n] = B[(size_t)(n0 + n) * K + k0 + k];
        }
        __syncthreads();
        #pragma unroll
        for (int k = 0; k < 32; ++k) {
            const float4 a = *(const float4*)&As[k][ty * 4];
            const float4 b = *(const float4*)&Bs[k][tx * 4];
            acc[0][0] = fmaf(a.x, b.x, acc[0][0]);
            acc[0][1] = fmaf(a.x, b.y, acc[0][1]);
            acc[0][2] = fmaf(a.x, b.z, acc[0][2]);
            acc[0][3] = fmaf(a.x, b.w, acc[0][3]);
            acc[1][0] = fmaf(a.y, b.x, acc[1][0]);
            acc[1][1] = fmaf(a.y, b.y, acc[1][1]);
            acc[1][2] = fmaf(a.y, b.z, acc[1][2]);
            acc[1][3] = fmaf(a.y, b.w, acc[1][3]);
            acc[2][0] = fmaf(a.z, b.x, acc[2][0]);
            acc[2][1] = fmaf(a.z, b.y, acc[2][1]);
            acc[2][2] = fmaf(a.z, b.z, acc[2][2]);
            acc[2][3] = fmaf(a.z, b.w, acc[2][3]);
            acc[3][0] = fmaf(a.w, b.x, acc[3][0]);
            acc[3][1] = fmaf(a.w, b.y, acc[3][1]);
            acc[3][2] = fmaf(a.w, b.z, acc[3][2]);
            acc[3][3] = fmaf(a.w, b.w, acc[3][3]);
        }
        __syncthreads();
    }

    float* pbase = partial + (size_t)blockIdx.z * M * N;
    #pragma unroll
    for (int i = 0; i < 4; ++i) {
        float4 o = make_float4(acc[i][0], acc[i][1], acc[i][2], acc[i][3]);
        *(float4*)&pbase[(size_t)(m0 + ty * 4 + i) * N + n0 + tx * 4] = o;
    }
}

// out[m][n] = act(sum_s partial[s][m][n] + bias[n])
__global__ __launch_bounds__(256) void gemm_reduce_k(
    const float* __restrict__ partial, const float* __restrict__ bias,
    float* __restrict__ out, int MN, int N, int S, int relu)
{
    const int idx = blockIdx.x * 256 + threadIdx.x;
    if (idx >= MN) return;
    float s = bias[idx % N];
    for (int i = 0; i < S; ++i) s += partial[(size_t)i * MN + idx];
    if (relu) s = fmaxf(s, 0.f);
    out[idx] = s;
}

// ---------------------------------------------------------------------------
// CBAM (with leading relu)  (UNCHANGED)
// ---------------------------------------------------------------------------
__global__ __launch_bounds__(256) void cbam_k(
    const float* __restrict__ in, const float* __restrict__ fc1,
    const float* __restrict__ fc2, const float* __restrict__ spw,
    float* __restrict__ out)
{
    __shared__ float xl[32][257];
    __shared__ float cmean[32], cmax[32], hidm[8], hidx[8], ca[32];
    __shared__ float spm[256], spx[256], sa[256];
    const int n = blockIdx.x, tid = threadIdx.x;
    const float* inN = in + (size_t)n * 8192;
    for (int c = 0; c < 32; ++c) xl[c][tid] = fmaxf(inN[c * 256 + tid], 0.f);
    __syncthreads();
    if (tid < 32) {
        float s = 0.f, m = -FLT_MAX;
        for (int p = 0; p < 256; ++p) { float v = xl[tid][p]; s += v; m = fmaxf(m, v); }
        cmean[tid] = s * (1.f / 256.f); cmax[tid] = m;
    }
    __syncthreads();
    if (tid < 8) {
        float sm = 0.f, sx = 0.f;
        for (int c = 0; c < 32; ++c) {
            float f = fc1[tid * 32 + c];
            sm += f * cmean[c]; sx += f * cmax[c];
        }
        hidm[tid] = fmaxf(sm, 0.f); hidx[tid] = fmaxf(sx, 0.f);
    }
    __syncthreads();
    if (tid < 32) {
        float s = 0.f;
        for (int h = 0; h < 8; ++h) s += fc2[tid * 8 + h] * (hidm[h] + hidx[h]);
        ca[tid] = 1.f / (1.f + expf(-s));
    }
    __syncthreads();
    {
        float s = 0.f, m = -FLT_MAX;
        for (int c = 0; c < 32; ++c) {
            float v = xl[c][tid] * ca[c];
            xl[c][tid] = v;
            s += v; m = fmaxf(m, v);
        }
        spm[tid] = s * (1.f / 32.f); spx[tid] = m;
    }
    __syncthreads();
    {
        const int y = tid >> 4, x = tid & 15;
        float s = 0.f;
        for (int ky = 0; ky < 7; ++ky) {
            const int yy = y + ky - 3;
            if (yy < 0 || yy >= 16) continue;
            for (int kx = 0; kx < 7; ++kx) {
                const int xx = x + kx - 3;
                if (xx < 0 || xx >= 16) continue;
                const int p = yy * 16 + xx;
                s += spm[p] * spw[ky * 7 + kx] + spx[p] * spw[49 + ky * 7 + kx];
            }
        }
        sa[tid] = 1.f / (1.f + expf(-s));
    }
    __syncthreads();
    float* outN = out + (size_t)n * 8192;
    const float sav = sa[tid];
    for (int c = 0; c < 32; ++c) outN[c * 256 + tid] = xl[c][tid] * sav;
}

// ---------------------------------------------------------------------------
// GRU scan  (UNCHANGED)
// ---------------------------------------------------------------------------
__global__ __launch_bounds__(384) void gru_k(
    const float* __restrict__ gi, const float* __restrict__ done,
    const float* __restrict__ h0, const float* __restrict__ whh,
    const float* __restrict__ bhh, float* __restrict__ hidden)
{
    const int b = blockIdx.x, j = threadIdx.x;
    __shared__ __align__(16) float hl[128];
    __shared__ float gh[384];
    float4 wr[32];
    const float4* wrow = (const float4*)(whh + (size_t)j * 128);
    #pragma unroll
    for (int i = 0; i < 32; ++i) wr[i] = wrow[i];
    const float bj = bhh[j];
    if (j < 128) hl[j] = h0[b * 128 + j];
    __syncthreads();
    for (int t = 0; t < 64; ++t) {
        const int rowi = t * 8 + b;
        const float dmask = 1.f - done[rowi];
        if (j < 128) hl[j] *= dmask;
        __syncthreads();
        float s = bj;
        const float4* h4 = (const float4*)hl;
        #pragma unroll
        for (int i = 0; i < 32; ++i) {
            const float4 h = h4[i];
            s = fmaf(wr[i].x, h.x, s);
            s = fmaf(wr[i].y, h.y, s);
            s = fmaf(wr[i].z, h.z, s);
            s = fmaf(wr[i].w, h.w, s);
        }
        gh[j] = s;
        __syncthreads();
        if (j < 128) {
            const float* gir = gi + (size_t)rowi * 384;
            const float r = 1.f / (1.f + expf(-(gir[j] + gh[j])));
            const float z = 1.f / (1.f + expf(-(gir[128 + j] + gh[128 + j])));
            const float nn = tanhf(gir[256 + j] + r * gh[256 + j]);
            const float hm = hl[j];
            const float hn = (1.f - z) * nn + z * hm;
            hl[j] = hn;
            hidden[(size_t)rowi * 128 + j] = hn;
        }
        __syncthreads();
    }
}

// ---------------------------------------------------------------------------
// actor/critic heads  (UNCHANGED)
// ---------------------------------------------------------------------------
__global__ __launch_bounds__(256) void heads_k(
    const float* __restrict__ hidden, const float* __restrict__ aw,
    const float* __restrict__ ab, const float* __restrict__ cw,
    const float* __restrict__ cb, float* __restrict__ out)
{
    const int idx = blockIdx.x * 256 + threadIdx.x;  // 2048
    const int m = idx >> 2, c = idx & 3;
    const float* h = hidden + (size_t)m * 128;
    const float* w = (c < 3) ? (aw + (size_t)c * 128) : cw;
    float s = (c < 3) ? ab[c] : cb[0];
    for (int k = 0; k < 128; ++k) s = fmaf(h[k], w[k], s);
    out[idx] = s;
}

// ---------------------------------------------------------------------------
extern "C" void kernel_launch(void* const* d_in, const int* in_sizes, int n_in,
                              void* d_out, int out_size, void* d_ws, size_t ws_size,
                              hipStream_t stream)
{
    const float* x      = (const float*)d_in[0];
    const float* done   = (const float*)d_in[1];
    const float* gstate = (const float*)d_in[2];
    const float* s0_cw  = (const float*)d_in[3];
    const float* s0_cb  = (const float*)d_in[4];
    const float* s0_rw  = (const float*)d_in[5];
    const float* s0_rb  = (const float*)d_in[6];
    const float* s1_cw  = (const float*)d_in[7];
    const float* s1_cb  = (const float*)d_in[8];
    const float* s1_rw  = (const float*)d_in[9];
    const float* s1_rb  = (const float*)d_in[10];
    const float* s2_cw  = (const float*)d_in[11];
    const float* s2_cb  = (const float*)d_in[12];
    const float* s2_rw  = (const float*)d_in[13];
    const float* s2_rb  = (const float*)d_in[14];
    const float* cfc1   = (const float*)d_in[15];
    const float* cfc2   = (const float*)d_in[16];
    const float* cspw   = (const float*)d_in[17];
    const float* fc_w   = (const float*)d_in[18];
    const float* fc_b   = (const float*)d_in[19];
    const float* gwih   = (const float*)d_in[20];
    const float* gwhh   = (const float*)d_in[21];
    const float* gbih   = (const float*)d_in[22];
    const float* gbhh   = (const float*)d_in[23];
    const float* aw     = (const float*)d_in[24];
    const float* ab     = (const float*)d_in[25];
    const float* cwt    = (const float*)d_in[26];
    const float* cbs    = (const float*)d_in[27];
    float* out = (float*)d_out;
    float* ws  = (float*)d_ws;

    // ws layout (floats); peak ~268 MB
    float* P0 = ws;                 // 33,554,432 floats
    float* T  = ws + 33554432;      // 33,554,432 floats
    float* S1P = T + 16777216;      // s1 pool out (16,777,216)
    float* X0  = P0 + 16777216;     // s2 pool out (4,194,304)
    float* TM  = P0 + 20971520;     // s2 res tmp  (4,194,304)
    float* CBO = P0 + 25165824;     // cbam out    (4,194,304)

    // ---- stage 0: entry conv (6->16, 128x128) + pool, chunks of 64 images ----
    for (int c = 0; c < 8; ++c) {
        const float* xin = x + (size_t)c * 64 * 6 * 128 * 128;
        conv3x3_k<6, 16><<<dim3(64, 64), 256, 0, stream>>>(xin, s0_cw, s0_cb, nullptr, T, 128, 8, 0);
        maxpool_k<<<(64 * 16 * 64 * 64) / 256, 256, 0, stream>>>(T, P0 + (size_t)c * 4194304, 64 * 16, 128);
    }
    // ---- stage 0 resblocks (16ch, 64x64) ----
    {
        const int RW = 16 * 16 * 9;
        conv3x3_k<16, 16><<<dim3(16, 512), 256, 0, stream>>>(P0, s0_rw + 0 * RW, s0_rb + 0,  nullptr, T,  64, 4, 1);
        conv3x3_k<16, 16><<<dim3(16, 512), 256, 0, stream>>>(T,  s0_rw + 1 * RW, s0_rb + 16, P0,      P0, 64, 4, 1);
        conv3x3_k<16, 16><<<dim3(16, 512), 256, 0, stream>>>(P0, s0_rw + 2 * RW, s0_rb + 32, nullptr, T,  64, 4, 1);
        conv3x3_k<16, 16><<<dim3(16, 512), 256, 0, stream>>>(T,  s0_rw + 3 * RW, s0_rb + 48, P0,      P0, 64, 4, 1);
    }
    // ---- stage 1: entry conv (16->32, 64x64) + pool, chunks of 128 images ----
    for (int c = 0; c < 4; ++c) {
        conv3x3_k<16, 32><<<dim3(16, 128), 256, 0, stream>>>(P0 + (size_t)c * 8388608, s1_cw, s1_cb, nullptr, T, 64, 4, 0);
        maxpool_k<<<16384, 256, 0, stream>>>(T, S1P + (size_t)c * 4194304, 128 * 32, 64);
    }
    // ---- stage 1 resblocks (32ch, 32x32) ----
    {
        const int RW = 32 * 32 * 9;
        conv3x3_k<32, 32><<<dim3(4, 512), 256, 0, stream>>>(S1P, s1_rw + 0 * RW, s1_rb + 0,  nullptr, P0,  32, 2, 1);
        conv3x3_k<32, 32><<<dim3(4, 512), 256, 0, stream>>>(P0,  s1_rw + 1 * RW, s1_rb + 32, S1P,     S1P, 32, 2, 1);
        conv3x3_k<32, 32><<<dim3(4, 512), 256, 0, stream>>>(S1P, s1_rw + 2 * RW, s1_rb + 64, nullptr, P0,  32, 2, 1);
        conv3x3_k<32, 32><<<dim3(4, 512), 256, 0, stream>>>(P0,  s1_rw + 3 * RW, s1_rb + 96, S1P,     S1P, 32, 2, 1);
    }
    // ---- stage 2: entry conv (32->32, 32x32) + pool ----
    conv3x3_k<32, 32><<<dim3(4, 512), 256, 0, stream>>>(S1P, s2_cw, s2_cb, nullptr, P0, 32, 2, 0);
    maxpool_k<<<16384, 256, 0, stream>>>(P0, X0, 512 * 32, 32);
    // ---- stage 2 resblocks (32ch, 16x16) ----
    {
        const int RW = 32 * 32 * 9;
        conv3x3_k<32, 32><<<dim3(1, 512), 256, 0, stream>>>(X0, s2_rw + 0 * RW, s2_rb + 0,  nullptr, TM, 16, 1, 1);
        conv3x3_k<32, 32><<<dim3(1, 512), 256, 0, stream>>>(TM, s2_rw + 1 * RW, s2_rb + 32, X0,      X0, 16, 1, 1);
        conv3x3_k<32, 32><<<dim3(1, 512), 256, 0, stream>>>(X0, s2_rw + 2 * RW, s2_rb + 64, nullptr, TM, 16, 1, 1);
        conv3x3_k<32, 32><<<dim3(1, 512), 256, 0, stream>>>(TM, s2_rw + 3 * RW, s2_rb + 96, X0,      X0, 16, 1, 1);
    }
    // ---- relu + CBAM ----
    cbam_k<<<512, 256, 0, stream>>>(X0, cfc1, cfc2, cspw, CBO);

    // ---- FC 8192->256 (+relu), split-K=32 (KC=256) ----
    float* FEAT = T;                        // 131072 floats
    float* GI   = T + 131072;               // 196608 floats
    float* HID  = T + 131072 + 196608;      // 65536 floats
    float* PART = T + 1048576;              // FC: 32*512*256 = 4,194,304 floats
    gemm_splitk_k<<<dim3(8, 4, 32), 256, 0, stream>>>(CBO, fc_w, PART, 512, 256, 8192, 256);
    gemm_reduce_k<<<512, 256, 0, stream>>>(PART, fc_b, FEAT, 512 * 256, 256, 32, 1);

    // ---- gi = feat @ Wih^T + bih, split-K=4 (KC=64) ----
    float* PARTG = T + 1048576 + 4194304;   // 4*512*384 = 786,432 floats
    gemm_splitk_k<<<dim3(8, 6, 4), 256, 0, stream>>>(FEAT, gwih, PARTG, 512, 384, 256, 64);
    gemm_reduce_k<<<768, 256, 0, stream>>>(PARTG, gbih, GI, 512 * 384, 384, 4, 0);

    // ---- GRU scan ----
    gru_k<<<8, 384, 0, stream>>>(GI, done, gstate, gwhh, gbhh, HID);
    // ---- heads ----
    heads_k<<<8, 256, 0, stream>>>(HID, aw, ab, cwt, cbs, out);
}

// Round 3
// 1407.163 us; speedup vs baseline: 3.9435x; 2.9942x over previous
//
#include <hip/hip_runtime.h>
#include <cstdint>
#include <cfloat>
#include <cmath>

typedef unsigned short ushort_t;
typedef short bf16x8 __attribute__((ext_vector_type(8)));
typedef float f32x4 __attribute__((ext_vector_type(4)));

__device__ inline ushort_t f2bf(float f) {
    union { float f; unsigned u; } v; v.f = f;
    return (ushort_t)((v.u + 0x7fffu + ((v.u >> 16) & 1u)) >> 16);   // RNE
}
__device__ inline float bf2f(ushort_t u) {
    union { unsigned u; float f; } v; v.u = ((unsigned)u) << 16;
    return v.f;
}
__device__ inline float bflo_f(unsigned w) { union { unsigned u; float f; } v; v.u = w << 16; return v.f; }
__device__ inline float bfhi_f(unsigned w) { union { unsigned u; float f; } v; v.u = w & 0xFFFF0000u; return v.f; }
__device__ inline unsigned relu2(unsigned p) {   // relu two packed bf16
    unsigned lo = (p & 0x8000u) ? 0u : (p & 0xFFFFu);
    unsigned hi = (p & 0x80000000u) ? 0u : (p & 0xFFFF0000u);
    return lo | hi;
}

// ---------------------------------------------------------------------------
// Weight prepack: fp32 OIHW -> bf16 [pos=ky*3+kx][co][cip] with cip padded to 32
// ---------------------------------------------------------------------------
struct PPJob { const float* src; ushort_t* dst; int ci; int co; };
struct PPArgs { PPJob j[15]; };

__global__ __launch_bounds__(256) void prepack_k(PPArgs a) {
    const PPJob p = a.j[blockIdx.x];
    const int tot = 9 * p.co * 32;
    for (int i = threadIdx.x; i < tot; i += 256) {
        const int cip = i & 31;
        const int rest = i >> 5;
        const int co = rest % p.co;
        const int pos = rest / p.co;
        float v = 0.f;
        if (cip < p.ci) v = p.src[(co * p.ci + cip) * 9 + pos];
        p.dst[i] = f2bf(v);
    }
}

// ---------------------------------------------------------------------------
// MFMA implicit-GEMM 3x3 conv, pad 1. NHWC bf16 in/out (or NCHW fp32 in).
// Tile 16x16 pixels per block, 4 waves; wave w computes tile rows 4w..4w+3.
// MFMA 16x16x32_bf16: M=16 pixel-cols, N=16 cos, K=32 ci (zero-padded).
// A from LDS (18x18 halo tile, pixel stride 40 ushorts -> bank step 20, 2-way
// conflicts = free); B (weights) fully register-resident: 0.5 ds_read/MFMA.
// Epilogue: +bias (fp32), optional skip-add (bf16), store bf16 NHWC.
// ---------------------------------------------------------------------------
template<int CIR, int CO, bool NCHWIN>
__global__ __launch_bounds__(256) void convm_k(
    const void* __restrict__ inv, const ushort_t* __restrict__ wp,
    const float* __restrict__ bias, const ushort_t* __restrict__ skip,
    ushort_t* __restrict__ out, int H, int TX, int relu_in)
{
    constexpr int NT = CO / 16;
    __shared__ __align__(16) ushort_t in_t[18 * 18 * 40];   // 25.9 KB

    const int n    = blockIdx.y;
    const int tile = blockIdx.x;
    const int ty0  = (tile / TX) * 16, tx0 = (tile % TX) * 16;
    const int tid  = threadIdx.x;
    const int lane = tid & 63, wv = tid >> 6;
    const int col  = lane & 15, oct = lane >> 4;

    // ---- B fragments (weights) -> registers ----
    bf16x8 bfrag[9][NT];
    #pragma unroll
    for (int p = 0; p < 9; ++p)
        #pragma unroll
        for (int t = 0; t < NT; ++t)
            bfrag[p][t] = *(const bf16x8*)&wp[(p * CO + t * 16 + col) * 32 + oct * 8];

    // ---- stage input tile (halo, zero-pad, optional relu) ----
    if constexpr (NCHWIN) {
        for (int i = tid; i < 18 * 18 * 40 / 8; i += 256)
            *(uint4*)&in_t[i * 8] = make_uint4(0, 0, 0, 0);
        __syncthreads();
        const float* gin = (const float*)inv;
        for (int i = tid; i < CIR * 324; i += 256) {
            const int ci = i / 324, px = i % 324;
            const int r = px / 18, c = px % 18;
            const int gy = ty0 - 1 + r, gx = tx0 - 1 + c;
            if ((unsigned)gy < (unsigned)H && (unsigned)gx < (unsigned)H)
                in_t[px * 40 + ci] = f2bf(gin[(((size_t)n * CIR + ci) * H + gy) * H + gx]);
        }
    } else {
        const ushort_t* gin = (const ushort_t*)inv;
        for (int i = tid; i < 324 * 4; i += 256) {
            const int px = i >> 2, oc = i & 3;
            const int r = px / 18, c = px % 18;
            const int gy = ty0 - 1 + r, gx = tx0 - 1 + c;
            uint4 v = make_uint4(0, 0, 0, 0);
            if (oc * 8 < CIR && (unsigned)gy < (unsigned)H && (unsigned)gx < (unsigned)H) {
                v = *(const uint4*)&gin[(((size_t)n * H + gy) * H + gx) * CIR + oc * 8];
                if (relu_in) { v.x = relu2(v.x); v.y = relu2(v.y); v.z = relu2(v.z); v.w = relu2(v.w); }
            }
            *(uint4*)&in_t[px * 40 + oc * 8] = v;
        }
    }
    __syncthreads();

    // ---- MFMA main loop: 9 positions x 4 rows x NT ----
    f32x4 acc[4][NT];
    #pragma unroll
    for (int r = 0; r < 4; ++r)
        #pragma unroll
        for (int t = 0; t < NT; ++t)
            acc[r][t] = (f32x4){0.f, 0.f, 0.f, 0.f};

    #pragma unroll
    for (int p = 0; p < 9; ++p) {
        const int ky = p / 3, kx = p % 3;
        #pragma unroll
        for (int r = 0; r < 4; ++r) {
            const int iy = wv * 4 + r + ky;        // 0..17
            const int ix = col + kx;               // 0..17
            const bf16x8 a = *(const bf16x8*)&in_t[(iy * 18 + ix) * 40 + oct * 8];
            #pragma unroll
            for (int t = 0; t < NT; ++t)
                acc[r][t] = __builtin_amdgcn_mfma_f32_16x16x32_bf16(a, bfrag[p][t], acc[r][t], 0, 0, 0);
        }
    }

    // ---- epilogue: bias + optional skip, bf16 NHWC store ----
    // C/D layout: n-dim(co)=lane&15, m-dim(pixel col)=(lane>>4)*4+reg
    float bv[NT];
    #pragma unroll
    for (int t = 0; t < NT; ++t) bv[t] = bias[t * 16 + col];
    #pragma unroll
    for (int r = 0; r < 4; ++r) {
        const int gy = ty0 + wv * 4 + r;
        #pragma unroll
        for (int t = 0; t < NT; ++t) {
            #pragma unroll
            for (int q = 0; q < 4; ++q) {
                const int gx = tx0 + oct * 4 + q;
                const size_t off = (((size_t)n * H + gy) * H + gx) * CO + t * 16 + col;
                float v = acc[r][t][q] + bv[t];
                if (skip) v += bf2f(skip[off]);
                out[off] = f2bf(v);
            }
        }
    }
}

// ---------------------------------------------------------------------------
// maxpool 3x3 stride 2 pad 1, NHWC bf16, 8 channels per thread
// ---------------------------------------------------------------------------
__global__ __launch_bounds__(256) void pool_nhwc_k(
    const ushort_t* __restrict__ in, ushort_t* __restrict__ out,
    int NI, int H, int C)
{
    const int HP = H >> 1, C8 = C >> 3;
    const long total = (long)NI * HP * HP * C8;
    long idx = (long)blockIdx.x * 256 + threadIdx.x;
    if (idx >= total) return;
    const int c8 = (int)(idx % C8); long r = idx / C8;
    const int px = (int)(r % HP); r /= HP;
    const int py = (int)(r % HP); const long n = r / HP;
    float m[8];
    #pragma unroll
    for (int k = 0; k < 8; ++k) m[k] = -FLT_MAX;
    for (int dy = 0; dy < 3; ++dy) {
        const int y = 2 * py - 1 + dy;
        if ((unsigned)y >= (unsigned)H) continue;
        for (int dx = 0; dx < 3; ++dx) {
            const int x = 2 * px - 1 + dx;
            if ((unsigned)x >= (unsigned)H) continue;
            const uint4 v = *(const uint4*)&in[(((long)n * H + y) * H + x) * C + c8 * 8];
            m[0] = fmaxf(m[0], bflo_f(v.x)); m[1] = fmaxf(m[1], bfhi_f(v.x));
            m[2] = fmaxf(m[2], bflo_f(v.y)); m[3] = fmaxf(m[3], bfhi_f(v.y));
            m[4] = fmaxf(m[4], bflo_f(v.z)); m[5] = fmaxf(m[5], bfhi_f(v.z));
            m[6] = fmaxf(m[6], bflo_f(v.w)); m[7] = fmaxf(m[7], bfhi_f(v.w));
        }
    }
    uint4 o;
    o.x = (unsigned)f2bf(m[0]) | ((unsigned)f2bf(m[1]) << 16);
    o.y = (unsigned)f2bf(m[2]) | ((unsigned)f2bf(m[3]) << 16);
    o.z = (unsigned)f2bf(m[4]) | ((unsigned)f2bf(m[5]) << 16);
    o.w = (unsigned)f2bf(m[6]) | ((unsigned)f2bf(m[7]) << 16);
    *(uint4*)&out[(((long)n * HP + py) * HP + px) * C + c8 * 8] = o;
}

// ---------------------------------------------------------------------------
// Split-K GEMM + reduce (fp32, unchanged from round 2)
// ---------------------------------------------------------------------------
__global__ __launch_bounds__(256) void gemm_splitk_k(
    const float* __restrict__ A, const float* __restrict__ B,
    float* __restrict__ partial, int M, int N, int K, int KC)
{
    __shared__ __align__(16) float As[32][65];
    __shared__ __align__(16) float Bs[32][65];
    const int m0 = blockIdx.x * 64, n0 = blockIdx.y * 64;
    const int kbase = blockIdx.z * KC;
    const int tid = threadIdx.x;
    const int tx = tid & 15, ty = tid >> 4;

    float acc[4][4];
    #pragma unroll
    for (int i = 0; i < 4; ++i)
        #pragma unroll
        for (int j = 0; j < 4; ++j) acc[i][j] = 0.f;

    for (int k0 = kbase; k0 < kbase + KC; k0 += 32) {
        for (int i = tid; i < 64 * 32; i += 256) {
            const int m = i >> 5, k = i & 31;
            As[k][m] = A[(size_t)(m0 + m) * K + k0 + k];
        }
        for (int i = tid; i < 64 * 32; i += 256) {
            const int nn = i >> 5, k = i & 31;
            Bs[k][nn] = B[(size_t)(n0 + nn) * K + k0 + k];
        }
        __syncthreads();
        #pragma unroll
        for (int k = 0; k < 32; ++k) {
            const float4 a = *(const float4*)&As[k][ty * 4];
            const float4 b = *(const float4*)&Bs[k][tx * 4];
            acc[0][0] = fmaf(a.x, b.x, acc[0][0]);
            acc[0][1] = fmaf(a.x, b.y, acc[0][1]);
            acc[0][2] = fmaf(a.x, b.z, acc[0][2]);
            acc[0][3] = fmaf(a.x, b.w, acc[0][3]);
            acc[1][0] = fmaf(a.y, b.x, acc[1][0]);
            acc[1][1] = fmaf(a.y, b.y, acc[1][1]);
            acc[1][2] = fmaf(a.y, b.z, acc[1][2]);
            acc[1][3] = fmaf(a.y, b.w, acc[1][3]);
            acc[2][0] = fmaf(a.z, b.x, acc[2][0]);
            acc[2][1] = fmaf(a.z, b.y, acc[2][1]);
            acc[2][2] = fmaf(a.z, b.z, acc[2][2]);
            acc[2][3] = fmaf(a.z, b.w, acc[2][3]);
            acc[3][0] = fmaf(a.w, b.x, acc[3][0]);
            acc[3][1] = fmaf(a.w, b.y, acc[3][1]);
            acc[3][2] = fmaf(a.w, b.z, acc[3][2]);
            acc[3][3] = fmaf(a.w, b.w, acc[3][3]);
        }
        __syncthreads();
    }

    float* pbase = partial + (size_t)blockIdx.z * M * N;
    #pragma unroll
    for (int i = 0; i < 4; ++i) {
        float4 o = make_float4(acc[i][0], acc[i][1], acc[i][2], acc[i][3]);
        *(float4*)&pbase[(size_t)(m0 + ty * 4 + i) * N + n0 + tx * 4] = o;
    }
}

__global__ __launch_bounds__(256) void gemm_reduce_k(
    const float* __restrict__ partial, const float* __restrict__ bias,
    float* __restrict__ out, int MN, int N, int S, int relu)
{
    const int idx = blockIdx.x * 256 + threadIdx.x;
    if (idx >= MN) return;
    float s = bias[idx % N];
    for (int i = 0; i < S; ++i) s += partial[(size_t)i * MN + idx];
    if (relu) s = fmaxf(s, 0.f);
    out[idx] = s;
}

// ---------------------------------------------------------------------------
// CBAM (leading relu): input NHWC bf16, output NCHW fp32
// ---------------------------------------------------------------------------
__global__ __launch_bounds__(256) void cbam_k(
    const ushort_t* __restrict__ in, const float* __restrict__ fc1,
    const float* __restrict__ fc2, const float* __restrict__ spw,
    float* __restrict__ out)
{
    __shared__ float xl[32][257];
    __shared__ float cmean[32], cmax[32], hidm[8], hidx[8], ca[32];
    __shared__ float spm[256], spx[256], sa[256];
    const int n = blockIdx.x, tid = threadIdx.x;
    const ushort_t* inN = in + (size_t)n * 8192;
    #pragma unroll
    for (int c8 = 0; c8 < 4; ++c8) {
        const uint4 v = *(const uint4*)&inN[tid * 32 + c8 * 8];
        xl[c8 * 8 + 0][tid] = fmaxf(bflo_f(v.x), 0.f);
        xl[c8 * 8 + 1][tid] = fmaxf(bfhi_f(v.x), 0.f);
        xl[c8 * 8 + 2][tid] = fmaxf(bflo_f(v.y), 0.f);
        xl[c8 * 8 + 3][tid] = fmaxf(bfhi_f(v.y), 0.f);
        xl[c8 * 8 + 4][tid] = fmaxf(bflo_f(v.z), 0.f);
        xl[c8 * 8 + 5][tid] = fmaxf(bfhi_f(v.z), 0.f);
        xl[c8 * 8 + 6][tid] = fmaxf(bflo_f(v.w), 0.f);
        xl[c8 * 8 + 7][tid] = fmaxf(bfhi_f(v.w), 0.f);
    }
    __syncthreads();
    if (tid < 32) {
        float s = 0.f, m = -FLT_MAX;
        for (int p = 0; p < 256; ++p) { float v = xl[tid][p]; s += v; m = fmaxf(m, v); }
        cmean[tid] = s * (1.f / 256.f); cmax[tid] = m;
    }
    __syncthreads();
    if (tid < 8) {
        float sm = 0.f, sx = 0.f;
        for (int c = 0; c < 32; ++c) {
            float f = fc1[tid * 32 + c];
            sm += f * cmean[c]; sx += f * cmax[c];
        }
        hidm[tid] = fmaxf(sm, 0.f); hidx[tid] = fmaxf(sx, 0.f);
    }
    __syncthreads();
    if (tid < 32) {
        float s = 0.f;
        for (int h = 0; h < 8; ++h) s += fc2[tid * 8 + h] * (hidm[h] + hidx[h]);
        ca[tid] = 1.f / (1.f + expf(-s));
    }
    __syncthreads();
    {
        float s = 0.f, m = -FLT_MAX;
        for (int c = 0; c < 32; ++c) {
            float v = xl[c][tid] * ca[c];
            xl[c][tid] = v;
            s += v; m = fmaxf(m, v);
        }
        spm[tid] = s * (1.f / 32.f); spx[tid] = m;
    }
    __syncthreads();
    {
        const int y = tid >> 4, x = tid & 15;
        float s = 0.f;
        for (int ky = 0; ky < 7; ++ky) {
            const int yy = y + ky - 3;
            if (yy < 0 || yy >= 16) continue;
            for (int kx = 0; kx < 7; ++kx) {
                const int xx = x + kx - 3;
                if (xx < 0 || xx >= 16) continue;
                const int p = yy * 16 + xx;
                s += spm[p] * spw[ky * 7 + kx] + spx[p] * spw[49 + ky * 7 + kx];
            }
        }
        sa[tid] = 1.f / (1.f + expf(-s));
    }
    __syncthreads();
    float* outN = out + (size_t)n * 8192;
    const float sav = sa[tid];
    for (int c = 0; c < 32; ++c) outN[c * 256 + tid] = xl[c][tid] * sav;
}

// ---------------------------------------------------------------------------
// GRU scan (unchanged)
// ---------------------------------------------------------------------------
__global__ __launch_bounds__(384) void gru_k(
    const float* __restrict__ gi, const float* __restrict__ done,
    const float* __restrict__ h0, const float* __restrict__ whh,
    const float* __restrict__ bhh, float* __restrict__ hidden)
{
    const int b = blockIdx.x, j = threadIdx.x;
    __shared__ __align__(16) float hl[128];
    __shared__ float gh[384];
    float4 wr[32];
    const float4* wrow = (const float4*)(whh + (size_t)j * 128);
    #pragma unroll
    for (int i = 0; i < 32; ++i) wr[i] = wrow[i];
    const float bj = bhh[j];
    if (j < 128) hl[j] = h0[b * 128 + j];
    __syncthreads();
    for (int t = 0; t < 64; ++t) {
        const int rowi = t * 8 + b;
        const float dmask = 1.f - done[rowi];
        if (j < 128) hl[j] *= dmask;
        __syncthreads();
        float s = bj;
        const float4* h4 = (const float4*)hl;
        #pragma unroll
        for (int i = 0; i < 32; ++i) {
            const float4 h = h4[i];
            s = fmaf(wr[i].x, h.x, s);
            s = fmaf(wr[i].y, h.y, s);
            s = fmaf(wr[i].z, h.z, s);
            s = fmaf(wr[i].w, h.w, s);
        }
        gh[j] = s;
        __syncthreads();
        if (j < 128) {
            const float* gir = gi + (size_t)rowi * 384;
            const float r = 1.f / (1.f + expf(-(gir[j] + gh[j])));
            const float z = 1.f / (1.f + expf(-(gir[128 + j] + gh[128 + j])));
            const float nn = tanhf(gir[256 + j] + r * gh[256 + j]);
            const float hm = hl[j];
            const float hn = (1.f - z) * nn + z * hm;
            hl[j] = hn;
            hidden[(size_t)rowi * 128 + j] = hn;
        }
        __syncthreads();
    }
}

// ---------------------------------------------------------------------------
// actor/critic heads (unchanged)
// ---------------------------------------------------------------------------
__global__ __launch_bounds__(256) void heads_k(
    const float* __restrict__ hidden, const float* __restrict__ aw,
    const float* __restrict__ ab, const float* __restrict__ cw,
    const float* __restrict__ cb, float* __restrict__ out)
{
    const int idx = blockIdx.x * 256 + threadIdx.x;  // 2048
    const int m = idx >> 2, c = idx & 3;
    const float* h = hidden + (size_t)m * 128;
    const float* w = (c < 3) ? (aw + (size_t)c * 128) : cw;
    float s = (c < 3) ? ab[c] : cb[0];
    for (int k = 0; k < 128; ++k) s = fmaf(h[k], w[k], s);
    out[idx] = s;
}

// ---------------------------------------------------------------------------
extern "C" void kernel_launch(void* const* d_in, const int* in_sizes, int n_in,
                              void* d_out, int out_size, void* d_ws, size_t ws_size,
                              hipStream_t stream)
{
    const float* x      = (const float*)d_in[0];
    const float* done   = (const float*)d_in[1];
    const float* gstate = (const float*)d_in[2];
    const float* s0_cw  = (const float*)d_in[3];
    const float* s0_cb  = (const float*)d_in[4];
    const float* s0_rw  = (const float*)d_in[5];
    const float* s0_rb  = (const float*)d_in[6];
    const float* s1_cw  = (const float*)d_in[7];
    const float* s1_cb  = (const float*)d_in[8];
    const float* s1_rw  = (const float*)d_in[9];
    const float* s1_rb  = (const float*)d_in[10];
    const float* s2_cw  = (const float*)d_in[11];
    const float* s2_cb  = (const float*)d_in[12];
    const float* s2_rw  = (const float*)d_in[13];
    const float* s2_rb  = (const float*)d_in[14];
    const float* cfc1   = (const float*)d_in[15];
    const float* cfc2   = (const float*)d_in[16];
    const float* cspw   = (const float*)d_in[17];
    const float* fc_w   = (const float*)d_in[18];
    const float* fc_b   = (const float*)d_in[19];
    const float* gwih   = (const float*)d_in[20];
    const float* gwhh   = (const float*)d_in[21];
    const float* gbih   = (const float*)d_in[22];
    const float* gbhh   = (const float*)d_in[23];
    const float* aw     = (const float*)d_in[24];
    const float* ab     = (const float*)d_in[25];
    const float* cwt    = (const float*)d_in[26];
    const float* cbs    = (const float*)d_in[27];
    float* out = (float*)d_out;

    // ---- ws layout (ushort units); peak ~176.4 MB ----
    ushort_t* wsu = (ushort_t*)d_ws;
    ushort_t* SCR = wsu;                       // 33,554,432 u (67.1 MB) scratch/tmp
    ushort_t* U1  = wsu + 33554432;            // 33,554,432 u (67.1 MB) s0 x
    ushort_t* U3  = wsu + 67108864;            // 16,777,216 u (33.5 MB) s1 x
    ushort_t* X0  = wsu + 83886080;            //  4,194,304 u ( 8.4 MB) s2 x
    ushort_t* WP  = wsu + 88080384;            //    131,072 u  weights
    // fp32 misc (placed in U1 region, free by FC time); CBO in SCR region
    float* CBO   = (float*)SCR;                // 4,194,304 f
    float* PART  = (float*)U1;                 // 4,194,304 f
    float* FEAT  = PART + 4194304;             //   131,072 f
    float* GI    = FEAT + 131072;              //   196,608 f
    float* PARTG = GI + 196608;                //   786,432 f
    float* HID   = PARTG + 786432;             //    65,536 f

    // ---- prepack all 15 conv weight tensors ----
    ushort_t* wp_s0e = WP;                       // 4608
    ushort_t* wp_s0r = WP + 4608;                // 4 x 4608
    ushort_t* wp_s1e = WP + 23040;               // 9216
    ushort_t* wp_s1r = WP + 32256;               // 4 x 9216
    ushort_t* wp_s2e = WP + 69120;               // 9216
    ushort_t* wp_s2r = WP + 78336;               // 4 x 9216
    {
        PPArgs a;
        a.j[0] = {s0_cw, wp_s0e, 6, 16};
        for (int i = 0; i < 4; ++i) a.j[1 + i] = {s0_rw + i * 2304, wp_s0r + i * 4608, 16, 16};
        a.j[5] = {s1_cw, wp_s1e, 16, 32};
        for (int i = 0; i < 4; ++i) a.j[6 + i] = {s1_rw + i * 9216, wp_s1r + i * 9216, 32, 32};
        a.j[10] = {s2_cw, wp_s2e, 32, 32};
        for (int i = 0; i < 4; ++i) a.j[11 + i] = {s2_rw + i * 9216, wp_s2r + i * 9216, 32, 32};
        prepack_k<<<15, 256, 0, stream>>>(a);
    }

    // ---- stage 0: entry conv (6->16 @128) + pool, 4 chunks of 128 images ----
    for (int c = 0; c < 4; ++c) {
        const float* xin = x + (size_t)c * 128 * 6 * 128 * 128;
        convm_k<6, 16, true><<<dim3(64, 128), 256, 0, stream>>>(
            xin, wp_s0e, s0_cb, nullptr, SCR, 128, 8, 0);
        pool_nhwc_k<<<4096, 256, 0, stream>>>(SCR, U1 + (size_t)c * 8388608, 128, 128, 16);
    }
    // ---- stage 0 resblocks (16ch @64) ----
    convm_k<16, 16, false><<<dim3(16, 512), 256, 0, stream>>>(U1,  wp_s0r + 0 * 4608, s0_rb + 0,  nullptr, SCR, 64, 4, 1);
    convm_k<16, 16, false><<<dim3(16, 512), 256, 0, stream>>>(SCR, wp_s0r + 1 * 4608, s0_rb + 16, U1,      U1,  64, 4, 1);
    convm_k<16, 16, false><<<dim3(16, 512), 256, 0, stream>>>(U1,  wp_s0r + 2 * 4608, s0_rb + 32, nullptr, SCR, 64, 4, 1);
    convm_k<16, 16, false><<<dim3(16, 512), 256, 0, stream>>>(SCR, wp_s0r + 3 * 4608, s0_rb + 48, U1,      U1,  64, 4, 1);
    // ---- stage 1: entry conv (16->32 @64) + pool, 2 chunks of 256 images ----
    for (int c = 0; c < 2; ++c) {
        convm_k<16, 32, false><<<dim3(16, 256), 256, 0, stream>>>(
            U1 + (size_t)c * 16777216, wp_s1e, s1_cb, nullptr, SCR, 64, 4, 0);
        pool_nhwc_k<<<4096, 256, 0, stream>>>(SCR, U3 + (size_t)c * 8388608, 256, 64, 32);
    }
    // ---- stage 1 resblocks (32ch @32) ----
    convm_k<32, 32, false><<<dim3(4, 512), 256, 0, stream>>>(U3,  wp_s1r + 0 * 9216, s1_rb + 0,  nullptr, SCR, 32, 2, 1);
    convm_k<32, 32, false><<<dim3(4, 512), 256, 0, stream>>>(SCR, wp_s1r + 1 * 9216, s1_rb + 32, U3,      U3,  32, 2, 1);
    convm_k<32, 32, false><<<dim3(4, 512), 256, 0, stream>>>(U3,  wp_s1r + 2 * 9216, s1_rb + 64, nullptr, SCR, 32, 2, 1);
    convm_k<32, 32, false><<<dim3(4, 512), 256, 0, stream>>>(SCR, wp_s1r + 3 * 9216, s1_rb + 96, U3,      U3,  32, 2, 1);
    // ---- stage 2: entry conv (32->32 @32) + pool ----
    convm_k<32, 32, false><<<dim3(4, 512), 256, 0, stream>>>(U3, wp_s2e, s2_cb, nullptr, SCR, 32, 2, 0);
    pool_nhwc_k<<<2048, 256, 0, stream>>>(SCR, X0, 512, 32, 32);
    // ---- stage 2 resblocks (32ch @16) ----
    convm_k<32, 32, false><<<dim3(1, 512), 256, 0, stream>>>(X0,  wp_s2r + 0 * 9216, s2_rb + 0,  nullptr, SCR, 16, 1, 1);
    convm_k<32, 32, false><<<dim3(1, 512), 256, 0, stream>>>(SCR, wp_s2r + 1 * 9216, s2_rb + 32, X0,      X0,  16, 1, 1);
    convm_k<32, 32, false><<<dim3(1, 512), 256, 0, stream>>>(X0,  wp_s2r + 2 * 9216, s2_rb + 64, nullptr, SCR, 16, 1, 1);
    convm_k<32, 32, false><<<dim3(1, 512), 256, 0, stream>>>(SCR, wp_s2r + 3 * 9216, s2_rb + 96, X0,      X0,  16, 1, 1);
    // ---- relu + CBAM (NHWC bf16 -> NCHW fp32) ----
    cbam_k<<<512, 256, 0, stream>>>(X0, cfc1, cfc2, cspw, CBO);
    // ---- FC 8192->256 (+relu), split-K=32 ----
    gemm_splitk_k<<<dim3(8, 4, 32), 256, 0, stream>>>(CBO, fc_w, PART, 512, 256, 8192, 256);
    gemm_reduce_k<<<512, 256, 0, stream>>>(PART, fc_b, FEAT, 512 * 256, 256, 32, 1);
    // ---- gi = feat @ Wih^T + bih, split-K=4 ----
    gemm_splitk_k<<<dim3(8, 6, 4), 256, 0, stream>>>(FEAT, gwih, PARTG, 512, 384, 256, 64);
    gemm_reduce_k<<<768, 256, 0, stream>>>(PARTG, gbih, GI, 512 * 384, 384, 4, 0);
    // ---- GRU scan ----
    gru_k<<<8, 384, 0, stream>>>(GI, done, gstate, gwhh, gbhh, HID);
    // ---- heads ----
    heads_k<<<8, 256, 0, stream>>>(HID, aw, ab, cwt, cbs, out);
}

// Round 4
// 1338.502 us; speedup vs baseline: 4.1458x; 1.0513x over previous
//
#include <hip/hip_runtime.h>
#include <cstdint>
#include <cfloat>
#include <cmath>

typedef unsigned short ushort_t;
typedef short bf16x8 __attribute__((ext_vector_type(8)));
typedef float f32x4 __attribute__((ext_vector_type(4)));

__device__ inline ushort_t f2bf(float f) {
    union { float f; unsigned u; } v; v.f = f;
    return (ushort_t)((v.u + 0x7fffu + ((v.u >> 16) & 1u)) >> 16);   // RNE
}
__device__ inline float bf2f(ushort_t u) {
    union { unsigned u; float f; } v; v.u = ((unsigned)u) << 16;
    return v.f;
}
__device__ inline float bflo_f(unsigned w) { union { unsigned u; float f; } v; v.u = w << 16; return v.f; }
__device__ inline float bfhi_f(unsigned w) { union { unsigned u; float f; } v; v.u = w & 0xFFFF0000u; return v.f; }
__device__ inline unsigned pk2(float a, float b) {
    return (unsigned)f2bf(a) | ((unsigned)f2bf(b) << 16);
}
__device__ inline unsigned relu2(unsigned p) {   // relu two packed bf16
    unsigned lo = (p & 0x8000u) ? 0u : (p & 0xFFFFu);
    unsigned hi = (p & 0x80000000u) ? 0u : (p & 0xFFFF0000u);
    return lo | hi;
}

// ---------------------------------------------------------------------------
// Weight prepack: fp32 OIHW -> bf16 [pos=ky*3+kx][co][cip] with cip padded to 32
// ---------------------------------------------------------------------------
struct PPJob { const float* src; ushort_t* dst; int ci; int co; };
struct PPArgs { PPJob j[15]; };

__global__ __launch_bounds__(256) void prepack_k(PPArgs a) {
    const PPJob p = a.j[blockIdx.x];
    const int tot = 9 * p.co * 32;
    for (int i = threadIdx.x; i < tot; i += 256) {
        const int cip = i & 31;
        const int rest = i >> 5;
        const int co = rest % p.co;
        const int pos = rest / p.co;
        float v = 0.f;
        if (cip < p.ci) v = p.src[(co * p.ci + cip) * 9 + pos];
        p.dst[i] = f2bf(v);
    }
}

// ---------------------------------------------------------------------------
// MFMA implicit-GEMM 3x3 conv, pad 1. NHWC bf16 in/out (or NCHW fp32 in).
// Tile 16x16 pixels per block, 4 waves; wave w computes pixel rows 4w..4w+3.
// MFMA 16x16x32_bf16 with A = weights (M=16 co), B = input (N=16 pixel cols),
// K=32 ci (zero-padded in the WEIGHT operand -> garbage ci in LDS is harmless).
// D layout: pixel = lane&15, co = (lane>>4)*4+reg -> each lane owns 4
// consecutive channels of one pixel => uint2 (4xbf16) epilogue stores/loads.
// B-frag from LDS (18x18 halo tile, pixel stride 40 ushorts -> bank step 20,
// 2-way conflicts = free); A-frag (weights) fully register-resident.
// ---------------------------------------------------------------------------
template<int CIR, int CO, bool NCHWIN>
__global__ __launch_bounds__(256) void convm_k(
    const void* __restrict__ inv, const ushort_t* __restrict__ wp,
    const float* __restrict__ bias, const ushort_t* __restrict__ skip,
    ushort_t* __restrict__ out, int H, int TX, int relu_in)
{
    constexpr int NT = CO / 16;
    __shared__ __align__(16) ushort_t in_t[18 * 18 * 40];   // 25.9 KB

    const int n    = blockIdx.y;
    const int tile = blockIdx.x;
    const int ty0  = (tile / TX) * 16, tx0 = (tile % TX) * 16;
    const int tid  = threadIdx.x;
    const int lane = tid & 63, wv = tid >> 6;
    const int col  = lane & 15, oct = lane >> 4;

    // ---- A fragments (weights) -> registers ----
    // element j = w[pos][co = t*16+col][ci = oct*8+j]  (A[m=lane&15][k=oct*8+j])
    bf16x8 wfrag[9][NT];
    #pragma unroll
    for (int p = 0; p < 9; ++p)
        #pragma unroll
        for (int t = 0; t < NT; ++t)
            wfrag[p][t] = *(const bf16x8*)&wp[(p * CO + t * 16 + col) * 32 + oct * 8];

    // ---- stage input tile (halo, zero-pad, optional relu) ----
    if constexpr (NCHWIN) {
        for (int i = tid; i < 18 * 18 * 40 / 8; i += 256)
            *(uint4*)&in_t[i * 8] = make_uint4(0, 0, 0, 0);
        __syncthreads();
        const float* gin = (const float*)inv;
        for (int i = tid; i < CIR * 324; i += 256) {
            const int ci = i / 324, px = i % 324;
            const int r = px / 18, c = px % 18;
            const int gy = ty0 - 1 + r, gx = tx0 - 1 + c;
            if ((unsigned)gy < (unsigned)H && (unsigned)gx < (unsigned)H)
                in_t[px * 40 + ci] = f2bf(gin[(((size_t)n * CIR + ci) * H + gy) * H + gx]);
        }
    } else {
        const ushort_t* gin = (const ushort_t*)inv;
        for (int i = tid; i < 324 * 4; i += 256) {
            const int px = i >> 2, oc = i & 3;
            const int r = px / 18, c = px % 18;
            const int gy = ty0 - 1 + r, gx = tx0 - 1 + c;
            uint4 v = make_uint4(0, 0, 0, 0);
            if (oc * 8 < CIR && (unsigned)gy < (unsigned)H && (unsigned)gx < (unsigned)H) {
                v = *(const uint4*)&gin[(((size_t)n * H + gy) * H + gx) * CIR + oc * 8];
                if (relu_in) { v.x = relu2(v.x); v.y = relu2(v.y); v.z = relu2(v.z); v.w = relu2(v.w); }
            }
            *(uint4*)&in_t[px * 40 + oc * 8] = v;
        }
    }
    __syncthreads();

    // ---- MFMA main loop: 9 positions x 4 pixel rows x NT co-tiles ----
    f32x4 acc[4][NT];
    #pragma unroll
    for (int r = 0; r < 4; ++r)
        #pragma unroll
        for (int t = 0; t < NT; ++t)
            acc[r][t] = (f32x4){0.f, 0.f, 0.f, 0.f};

    #pragma unroll
    for (int p = 0; p < 9; ++p) {
        const int ky = p / 3, kx = p % 3;
        #pragma unroll
        for (int r = 0; r < 4; ++r) {
            const int iy = wv * 4 + r + ky;        // 0..17
            const int ix = col + kx;               // 0..17
            const bf16x8 b = *(const bf16x8*)&in_t[(iy * 18 + ix) * 40 + oct * 8];
            #pragma unroll
            for (int t = 0; t < NT; ++t)
                acc[r][t] = __builtin_amdgcn_mfma_f32_16x16x32_bf16(wfrag[p][t], b, acc[r][t], 0, 0, 0);
        }
    }

    // ---- epilogue: bias + optional skip, vectorized bf16 NHWC store ----
    // lane owns pixel (gy, gx=tx0+col), channels t*16 + oct*4 + {0..3}
    float4 bv[NT];
    #pragma unroll
    for (int t = 0; t < NT; ++t) bv[t] = *(const float4*)&bias[t * 16 + oct * 4];
    #pragma unroll
    for (int r = 0; r < 4; ++r) {
        const int gy = ty0 + wv * 4 + r;
        const int gx = tx0 + col;
        const size_t pbase = (((size_t)n * H + gy) * H + gx) * CO + oct * 4;
        #pragma unroll
        for (int t = 0; t < NT; ++t) {
            float v0 = acc[r][t][0] + bv[t].x;
            float v1 = acc[r][t][1] + bv[t].y;
            float v2 = acc[r][t][2] + bv[t].z;
            float v3 = acc[r][t][3] + bv[t].w;
            if (skip) {
                const uint2 s = *(const uint2*)&skip[pbase + t * 16];
                v0 += bflo_f(s.x); v1 += bfhi_f(s.x);
                v2 += bflo_f(s.y); v3 += bfhi_f(s.y);
            }
            uint2 o;
            o.x = pk2(v0, v1);
            o.y = pk2(v2, v3);
            *(uint2*)&out[pbase + t * 16] = o;
        }
    }
}

// ---------------------------------------------------------------------------
// maxpool 3x3 stride 2 pad 1, NHWC bf16, 8 channels per thread
// ---------------------------------------------------------------------------
__global__ __launch_bounds__(256) void pool_nhwc_k(
    const ushort_t* __restrict__ in, ushort_t* __restrict__ out,
    int NI, int H, int C)
{
    const int HP = H >> 1, C8 = C >> 3;
    const long total = (long)NI * HP * HP * C8;
    long idx = (long)blockIdx.x * 256 + threadIdx.x;
    if (idx >= total) return;
    const int c8 = (int)(idx % C8); long r = idx / C8;
    const int px = (int)(r % HP); r /= HP;
    const int py = (int)(r % HP); const long n = r / HP;
    float m[8];
    #pragma unroll
    for (int k = 0; k < 8; ++k) m[k] = -FLT_MAX;
    for (int dy = 0; dy < 3; ++dy) {
        const int y = 2 * py - 1 + dy;
        if ((unsigned)y >= (unsigned)H) continue;
        for (int dx = 0; dx < 3; ++dx) {
            const int x = 2 * px - 1 + dx;
            if ((unsigned)x >= (unsigned)H) continue;
            const uint4 v = *(const uint4*)&in[(((long)n * H + y) * H + x) * C + c8 * 8];
            m[0] = fmaxf(m[0], bflo_f(v.x)); m[1] = fmaxf(m[1], bfhi_f(v.x));
            m[2] = fmaxf(m[2], bflo_f(v.y)); m[3] = fmaxf(m[3], bfhi_f(v.y));
            m[4] = fmaxf(m[4], bflo_f(v.z)); m[5] = fmaxf(m[5], bfhi_f(v.z));
            m[6] = fmaxf(m[6], bflo_f(v.w)); m[7] = fmaxf(m[7], bfhi_f(v.w));
        }
    }
    uint4 o;
    o.x = (unsigned)f2bf(m[0]) | ((unsigned)f2bf(m[1]) << 16);
    o.y = (unsigned)f2bf(m[2]) | ((unsigned)f2bf(m[3]) << 16);
    o.z = (unsigned)f2bf(m[4]) | ((unsigned)f2bf(m[5]) << 16);
    o.w = (unsigned)f2bf(m[6]) | ((unsigned)f2bf(m[7]) << 16);
    *(uint4*)&out[(((long)n * HP + py) * HP + px) * C + c8 * 8] = o;
}

// ---------------------------------------------------------------------------
// Split-K GEMM + reduce (fp32, unchanged)
// ---------------------------------------------------------------------------
__global__ __launch_bounds__(256) void gemm_splitk_k(
    const float* __restrict__ A, const float* __restrict__ B,
    float* __restrict__ partial, int M, int N, int K, int KC)
{
    __shared__ __align__(16) float As[32][65];
    __shared__ __align__(16) float Bs[32][65];
    const int m0 = blockIdx.x * 64, n0 = blockIdx.y * 64;
    const int kbase = blockIdx.z * KC;
    const int tid = threadIdx.x;
    const int tx = tid & 15, ty = tid >> 4;

    float acc[4][4];
    #pragma unroll
    for (int i = 0; i < 4; ++i)
        #pragma unroll
        for (int j = 0; j < 4; ++j) acc[i][j] = 0.f;

    for (int k0 = kbase; k0 < kbase + KC; k0 += 32) {
        for (int i = tid; i < 64 * 32; i += 256) {
            const int m = i >> 5, k = i & 31;
            As[k][m] = A[(size_t)(m0 + m) * K + k0 + k];
        }
        for (int i = tid; i < 64 * 32; i += 256) {
            const int nn = i >> 5, k = i & 31;
            Bs[k][nn] = B[(size_t)(n0 + nn) * K + k0 + k];
        }
        __syncthreads();
        #pragma unroll
        for (int k = 0; k < 32; ++k) {
            const float4 a = *(const float4*)&As[k][ty * 4];
            const float4 b = *(const float4*)&Bs[k][tx * 4];
            acc[0][0] = fmaf(a.x, b.x, acc[0][0]);
            acc[0][1] = fmaf(a.x, b.y, acc[0][1]);
            acc[0][2] = fmaf(a.x, b.z, acc[0][2]);
            acc[0][3] = fmaf(a.x, b.w, acc[0][3]);
            acc[1][0] = fmaf(a.y, b.x, acc[1][0]);
            acc[1][1] = fmaf(a.y, b.y, acc[1][1]);
            acc[1][2] = fmaf(a.y, b.z, acc[1][2]);
            acc[1][3] = fmaf(a.y, b.w, acc[1][3]);
            acc[2][0] = fmaf(a.z, b.x, acc[2][0]);
            acc[2][1] = fmaf(a.z, b.y, acc[2][1]);
            acc[2][2] = fmaf(a.z, b.z, acc[2][2]);
            acc[2][3] = fmaf(a.z, b.w, acc[2][3]);
            acc[3][0] = fmaf(a.w, b.x, acc[3][0]);
            acc[3][1] = fmaf(a.w, b.y, acc[3][1]);
            acc[3][2] = fmaf(a.w, b.z, acc[3][2]);
            acc[3][3] = fmaf(a.w, b.w, acc[3][3]);
        }
        __syncthreads();
    }

    float* pbase = partial + (size_t)blockIdx.z * M * N;
    #pragma unroll
    for (int i = 0; i < 4; ++i) {
        float4 o = make_float4(acc[i][0], acc[i][1], acc[i][2], acc[i][3]);
        *(float4*)&pbase[(size_t)(m0 + ty * 4 + i) * N + n0 + tx * 4] = o;
    }
}

__global__ __launch_bounds__(256) void gemm_reduce_k(
    const float* __restrict__ partial, const float* __restrict__ bias,
    float* __restrict__ out, int MN, int N, int S, int relu)
{
    const int idx = blockIdx.x * 256 + threadIdx.x;
    if (idx >= MN) return;
    float s = bias[idx % N];
    for (int i = 0; i < S; ++i) s += partial[(size_t)i * MN + idx];
    if (relu) s = fmaxf(s, 0.f);
    out[idx] = s;
}

// ---------------------------------------------------------------------------
// CBAM (leading relu): input NHWC bf16, output NCHW fp32  (unchanged)
// ---------------------------------------------------------------------------
__global__ __launch_bounds__(256) void cbam_k(
    const ushort_t* __restrict__ in, const float* __restrict__ fc1,
    const float* __restrict__ fc2, const float* __restrict__ spw,
    float* __restrict__ out)
{
    __shared__ float xl[32][257];
    __shared__ float cmean[32], cmax[32], hidm[8], hidx[8], ca[32];
    __shared__ float spm[256], spx[256], sa[256];
    const int n = blockIdx.x, tid = threadIdx.x;
    const ushort_t* inN = in + (size_t)n * 8192;
    #pragma unroll
    for (int c8 = 0; c8 < 4; ++c8) {
        const uint4 v = *(const uint4*)&inN[tid * 32 + c8 * 8];
        xl[c8 * 8 + 0][tid] = fmaxf(bflo_f(v.x), 0.f);
        xl[c8 * 8 + 1][tid] = fmaxf(bfhi_f(v.x), 0.f);
        xl[c8 * 8 + 2][tid] = fmaxf(bflo_f(v.y), 0.f);
        xl[c8 * 8 + 3][tid] = fmaxf(bfhi_f(v.y), 0.f);
        xl[c8 * 8 + 4][tid] = fmaxf(bflo_f(v.z), 0.f);
        xl[c8 * 8 + 5][tid] = fmaxf(bfhi_f(v.z), 0.f);
        xl[c8 * 8 + 6][tid] = fmaxf(bflo_f(v.w), 0.f);
        xl[c8 * 8 + 7][tid] = fmaxf(bfhi_f(v.w), 0.f);
    }
    __syncthreads();
    if (tid < 32) {
        float s = 0.f, m = -FLT_MAX;
        for (int p = 0; p < 256; ++p) { float v = xl[tid][p]; s += v; m = fmaxf(m, v); }
        cmean[tid] = s * (1.f / 256.f); cmax[tid] = m;
    }
    __syncthreads();
    if (tid < 8) {
        float sm = 0.f, sx = 0.f;
        for (int c = 0; c < 32; ++c) {
            float f = fc1[tid * 32 + c];
            sm += f * cmean[c]; sx += f * cmax[c];
        }
        hidm[tid] = fmaxf(sm, 0.f); hidx[tid] = fmaxf(sx, 0.f);
    }
    __syncthreads();
    if (tid < 32) {
        float s = 0.f;
        for (int h = 0; h < 8; ++h) s += fc2[tid * 8 + h] * (hidm[h] + hidx[h]);
        ca[tid] = 1.f / (1.f + expf(-s));
    }
    __syncthreads();
    {
        float s = 0.f, m = -FLT_MAX;
        for (int c = 0; c < 32; ++c) {
            float v = xl[c][tid] * ca[c];
            xl[c][tid] = v;
            s += v; m = fmaxf(m, v);
        }
        spm[tid] = s * (1.f / 32.f); spx[tid] = m;
    }
    __syncthreads();
    {
        const int y = tid >> 4, x = tid & 15;
        float s = 0.f;
        for (int ky = 0; ky < 7; ++ky) {
            const int yy = y + ky - 3;
            if (yy < 0 || yy >= 16) continue;
            for (int kx = 0; kx < 7; ++kx) {
                const int xx = x + kx - 3;
                if (xx < 0 || xx >= 16) continue;
                const int p = yy * 16 + xx;
                s += spm[p] * spw[ky * 7 + kx] + spx[p] * spw[49 + ky * 7 + kx];
            }
        }
        sa[tid] = 1.f / (1.f + expf(-s));
    }
    __syncthreads();
    float* outN = out + (size_t)n * 8192;
    const float sav = sa[tid];
    for (int c = 0; c < 32; ++c) outN[c * 256 + tid] = xl[c][tid] * sav;
}

// ---------------------------------------------------------------------------
// GRU scan (unchanged)
// ---------------------------------------------------------------------------
__global__ __launch_bounds__(384) void gru_k(
    const float* __restrict__ gi, const float* __restrict__ done,
    const float* __restrict__ h0, const float* __restrict__ whh,
    const float* __restrict__ bhh, float* __restrict__ hidden)
{
    const int b = blockIdx.x, j = threadIdx.x;
    __shared__ __align__(16) float hl[128];
    __shared__ float gh[384];
    float4 wr[32];
    const float4* wrow = (const float4*)(whh + (size_t)j * 128);
    #pragma unroll
    for (int i = 0; i < 32; ++i) wr[i] = wrow[i];
    const float bj = bhh[j];
    if (j < 128) hl[j] = h0[b * 128 + j];
    __syncthreads();
    for (int t = 0; t < 64; ++t) {
        const int rowi = t * 8 + b;
        const float dmask = 1.f - done[rowi];
        if (j < 128) hl[j] *= dmask;
        __syncthreads();
        float s = bj;
        const float4* h4 = (const float4*)hl;
        #pragma unroll
        for (int i = 0; i < 32; ++i) {
            const float4 h = h4[i];
            s = fmaf(wr[i].x, h.x, s);
            s = fmaf(wr[i].y, h.y, s);
            s = fmaf(wr[i].z, h.z, s);
            s = fmaf(wr[i].w, h.w, s);
        }
        gh[j] = s;
        __syncthreads();
        if (j < 128) {
            const float* gir = gi + (size_t)rowi * 384;
            const float r = 1.f / (1.f + expf(-(gir[j] + gh[j])));
            const float z = 1.f / (1.f + expf(-(gir[128 + j] + gh[128 + j])));
            const float nn = tanhf(gir[256 + j] + r * gh[256 + j]);
            const float hm = hl[j];
            const float hn = (1.f - z) * nn + z * hm;
            hl[j] = hn;
            hidden[(size_t)rowi * 128 + j] = hn;
        }
        __syncthreads();
    }
}

// ---------------------------------------------------------------------------
// actor/critic heads (unchanged)
// ---------------------------------------------------------------------------
__global__ __launch_bounds__(256) void heads_k(
    const float* __restrict__ hidden, const float* __restrict__ aw,
    const float* __restrict__ ab, const float* __restrict__ cw,
    const float* __restrict__ cb, float* __restrict__ out)
{
    const int idx = blockIdx.x * 256 + threadIdx.x;  // 2048
    const int m = idx >> 2, c = idx & 3;
    const float* h = hidden + (size_t)m * 128;
    const float* w = (c < 3) ? (aw + (size_t)c * 128) : cw;
    float s = (c < 3) ? ab[c] : cb[0];
    for (int k = 0; k < 128; ++k) s = fmaf(h[k], w[k], s);
    out[idx] = s;
}

// ---------------------------------------------------------------------------
extern "C" void kernel_launch(void* const* d_in, const int* in_sizes, int n_in,
                              void* d_out, int out_size, void* d_ws, size_t ws_size,
                              hipStream_t stream)
{
    const float* x      = (const float*)d_in[0];
    const float* done   = (const float*)d_in[1];
    const float* gstate = (const float*)d_in[2];
    const float* s0_cw  = (const float*)d_in[3];
    const float* s0_cb  = (const float*)d_in[4];
    const float* s0_rw  = (const float*)d_in[5];
    const float* s0_rb  = (const float*)d_in[6];
    const float* s1_cw  = (const float*)d_in[7];
    const float* s1_cb  = (const float*)d_in[8];
    const float* s1_rw  = (const float*)d_in[9];
    const float* s1_rb  = (const float*)d_in[10];
    const float* s2_cw  = (const float*)d_in[11];
    const float* s2_cb  = (const float*)d_in[12];
    const float* s2_rw  = (const float*)d_in[13];
    const float* s2_rb  = (const float*)d_in[14];
    const float* cfc1   = (const float*)d_in[15];
    const float* cfc2   = (const float*)d_in[16];
    const float* cspw   = (const float*)d_in[17];
    const float* fc_w   = (const float*)d_in[18];
    const float* fc_b   = (const float*)d_in[19];
    const float* gwih   = (const float*)d_in[20];
    const float* gwhh   = (const float*)d_in[21];
    const float* gbih   = (const float*)d_in[22];
    const float* gbhh   = (const float*)d_in[23];
    const float* aw     = (const float*)d_in[24];
    const float* ab     = (const float*)d_in[25];
    const float* cwt    = (const float*)d_in[26];
    const float* cbs    = (const float*)d_in[27];
    float* out = (float*)d_out;

    // ---- ws layout (ushort units); peak ~176.4 MB ----
    ushort_t* wsu = (ushort_t*)d_ws;
    ushort_t* SCR = wsu;                       // 33,554,432 u (67.1 MB) scratch/tmp
    ushort_t* U1  = wsu + 33554432;            // 33,554,432 u (67.1 MB) s0 x
    ushort_t* U3  = wsu + 67108864;            // 16,777,216 u (33.5 MB) s1 x
    ushort_t* X0  = wsu + 83886080;            //  4,194,304 u ( 8.4 MB) s2 x
    ushort_t* WP  = wsu + 88080384;            //    131,072 u  weights
    // fp32 misc (placed in U1 region, free by FC time); CBO in SCR region
    float* CBO   = (float*)SCR;                // 4,194,304 f
    float* PART  = (float*)U1;                 // 4,194,304 f
    float* FEAT  = PART + 4194304;             //   131,072 f
    float* GI    = FEAT + 131072;              //   196,608 f
    float* PARTG = GI + 196608;                //   786,432 f
    float* HID   = PARTG + 786432;             //    65,536 f

    // ---- prepack all 15 conv weight tensors ----
    ushort_t* wp_s0e = WP;                       // 4608
    ushort_t* wp_s0r = WP + 4608;                // 4 x 4608
    ushort_t* wp_s1e = WP + 23040;               // 9216
    ushort_t* wp_s1r = WP + 32256;               // 4 x 9216
    ushort_t* wp_s2e = WP + 69120;               // 9216
    ushort_t* wp_s2r = WP + 78336;               // 4 x 9216
    {
        PPArgs a;
        a.j[0] = {s0_cw, wp_s0e, 6, 16};
        for (int i = 0; i < 4; ++i) a.j[1 + i] = {s0_rw + i * 2304, wp_s0r + i * 4608, 16, 16};
        a.j[5] = {s1_cw, wp_s1e, 16, 32};
        for (int i = 0; i < 4; ++i) a.j[6 + i] = {s1_rw + i * 9216, wp_s1r + i * 9216, 32, 32};
        a.j[10] = {s2_cw, wp_s2e, 32, 32};
        for (int i = 0; i < 4; ++i) a.j[11 + i] = {s2_rw + i * 9216, wp_s2r + i * 9216, 32, 32};
        prepack_k<<<15, 256, 0, stream>>>(a);
    }

    // ---- stage 0: entry conv (6->16 @128) + pool, 4 chunks of 128 images ----
    for (int c = 0; c < 4; ++c) {
        const float* xin = x + (size_t)c * 128 * 6 * 128 * 128;
        convm_k<6, 16, true><<<dim3(64, 128), 256, 0, stream>>>(
            xin, wp_s0e, s0_cb, nullptr, SCR, 128, 8, 0);
        pool_nhwc_k<<<4096, 256, 0, stream>>>(SCR, U1 + (size_t)c * 8388608, 128, 128, 16);
    }
    // ---- stage 0 resblocks (16ch @64) ----
    convm_k<16, 16, false><<<dim3(16, 512), 256, 0, stream>>>(U1,  wp_s0r + 0 * 4608, s0_rb + 0,  nullptr, SCR, 64, 4, 1);
    convm_k<16, 16, false><<<dim3(16, 512), 256, 0, stream>>>(SCR, wp_s0r + 1 * 4608, s0_rb + 16, U1,      U1,  64, 4, 1);
    convm_k<16, 16, false><<<dim3(16, 512), 256, 0, stream>>>(U1,  wp_s0r + 2 * 4608, s0_rb + 32, nullptr, SCR, 64, 4, 1);
    convm_k<16, 16, false><<<dim3(16, 512), 256, 0, stream>>>(SCR, wp_s0r + 3 * 4608, s0_rb + 48, U1,      U1,  64, 4, 1);
    // ---- stage 1: entry conv (16->32 @64) + pool, 2 chunks of 256 images ----
    for (int c = 0; c < 2; ++c) {
        convm_k<16, 32, false><<<dim3(16, 256), 256, 0, stream>>>(
            U1 + (size_t)c * 16777216, wp_s1e, s1_cb, nullptr, SCR, 64, 4, 0);
        pool_nhwc_k<<<4096, 256, 0, stream>>>(SCR, U3 + (size_t)c * 8388608, 256, 64, 32);
    }
    // ---- stage 1 resblocks (32ch @32) ----
    convm_k<32, 32, false><<<dim3(4, 512), 256, 0, stream>>>(U3,  wp_s1r + 0 * 9216, s1_rb + 0,  nullptr, SCR, 32, 2, 1);
    convm_k<32, 32, false><<<dim3(4, 512), 256, 0, stream>>>(SCR, wp_s1r + 1 * 9216, s1_rb + 32, U3,      U3,  32, 2, 1);
    convm_k<32, 32, false><<<dim3(4, 512), 256, 0, stream>>>(U3,  wp_s1r + 2 * 9216, s1_rb + 64, nullptr, SCR, 32, 2, 1);
    convm_k<32, 32, false><<<dim3(4, 512), 256, 0, stream>>>(SCR, wp_s1r + 3 * 9216, s1_rb + 96, U3,      U3,  32, 2, 1);
    // ---- stage 2: entry conv (32->32 @32) + pool ----
    convm_k<32, 32, false><<<dim3(4, 512), 256, 0, stream>>>(U3, wp_s2e, s2_cb, nullptr, SCR, 32, 2, 0);
    pool_nhwc_k<<<2048, 256, 0, stream>>>(SCR, X0, 512, 32, 32);
    // ---- stage 2 resblocks (32ch @16) ----
    convm_k<32, 32, false><<<dim3(1, 512), 256, 0, stream>>>(X0,  wp_s2r + 0 * 9216, s2_rb + 0,  nullptr, SCR, 16, 1, 1);
    convm_k<32, 32, false><<<dim3(1, 512), 256, 0, stream>>>(SCR, wp_s2r + 1 * 9216, s2_rb + 32, X0,      X0,  16, 1, 1);
    convm_k<32, 32, false><<<dim3(1, 512), 256, 0, stream>>>(X0,  wp_s2r + 2 * 9216, s2_rb + 64, nullptr, SCR, 16, 1, 1);
    convm_k<32, 32, false><<<dim3(1, 512), 256, 0, stream>>>(SCR, wp_s2r + 3 * 9216, s2_rb + 96, X0,      X0,  16, 1, 1);
    // ---- relu + CBAM (NHWC bf16 -> NCHW fp32) ----
    cbam_k<<<512, 256, 0, stream>>>(X0, cfc1, cfc2, cspw, CBO);
    // ---- FC 8192->256 (+relu), split-K=32 ----
    gemm_splitk_k<<<dim3(8, 4, 32), 256, 0, stream>>>(CBO, fc_w, PART, 512, 256, 8192, 256);
    gemm_reduce_k<<<512, 256, 0, stream>>>(PART, fc_b, FEAT, 512 * 256, 256, 32, 1);
    // ---- gi = feat @ Wih^T + bih, split-K=4 ----
    gemm_splitk_k<<<dim3(8, 6, 4), 256, 0, stream>>>(FEAT, gwih, PARTG, 512, 384, 256, 64);
    gemm_reduce_k<<<768, 256, 0, stream>>>(PARTG, gbih, GI, 512 * 384, 384, 4, 0);
    // ---- GRU scan ----
    gru_k<<<8, 384, 0, stream>>>(GI, done, gstate, gwhh, gbhh, HID);
    // ---- heads ----
    heads_k<<<8, 256, 0, stream>>>(HID, aw, ab, cwt, cbs, out);
}